// Round 13
// baseline (2019.643 us; speedup 1.0000x reference)
//
#include <hip/hip_runtime.h>
#include <hip/hip_bf16.h>
#include <math.h>

#define DEVFN __device__ __forceinline__

constexpr int B_ = 16, N_ = 512, K_ = 30, H_ = 128;
constexpr int NH_ = 4, V_ = 20;
constexpr int BN_ = B_ * N_;
constexpr float NEG_INF_ = -3.4028235e38f;
constexpr int FRAG_ = H_ * H_;        // 16384 elems per 128x128 plane
constexpr int FRAG2_ = H_ * 4 * H_;   // 65536 elems per 128x512 / 512x128 plane

typedef unsigned short ushort_t;
using short8 = __attribute__((ext_vector_type(8))) short;
using f32x4  = __attribute__((ext_vector_type(4))) float;

DEVFN ushort_t bf16rn(float x) {
  unsigned u = __float_as_uint(x);
  return (ushort_t)((u + 0x7fffu + ((u >> 16) & 1u)) >> 16);
}
DEVFN float bf16tof(ushort_t h) { return __uint_as_float(((unsigned)h) << 16); }

// ---------------- top-K neighbors: distances BIT-EXACT to plain numpy float32 ----------------
// DO NOT TOUCH the distance math / tie-break. R6 rewrite: register-resident selection,
// 4 queries/block (1 wave each); zero barriers/LDS in the K-loop. Bit-identical output.
constexpr int TQ_ = 4;
__global__ __launch_bounds__(256) void topk_kernel(const float* __restrict__ X,
    const float* __restrict__ mask, int* __restrict__ E_idx, float* __restrict__ Dnb) {
  __shared__ float xs[N_ * 3];
  __shared__ float ms[N_];
  int blk = blockIdx.x;
  int b = blk / (N_ / TQ_);
  int i0 = (blk % (N_ / TQ_)) * TQ_;
  int t = threadIdx.x;
  int wv = t >> 6, l = t & 63;
  for (int j = t; j < N_; j += 256) {
    const float* p = X + ((size_t)(b * N_ + j) * 4 + 1) * 3;  // CA atom
    xs[j * 3 + 0] = p[0]; xs[j * 3 + 1] = p[1]; xs[j * 3 + 2] = p[2];
    ms[j] = mask[b * N_ + j];
  }
  __syncthreads();
  const int i = i0 + wv;
  const float xi0 = xs[i * 3], xi1 = xs[i * 3 + 1], xi2 = xs[i * 3 + 2];
  const float mi = ms[i];
  float D[8];
  float lmax = -3.4e38f;
  #pragma unroll
  for (int e = 0; e < 8; e++) {
    int j = l * 8 + e;
    float dx = __fsub_rn(xi0, xs[j * 3]);
    float dy = __fsub_rn(xi1, xs[j * 3 + 1]);
    float dz = __fsub_rn(xi2, xs[j * 3 + 2]);
    float m2 = __fmul_rn(mi, ms[j]);
    float s = __fadd_rn(__fadd_rn(__fadd_rn(__fmul_rn(dx, dx), __fmul_rn(dy, dy)),
                                  __fmul_rn(dz, dz)), 1e-6f);
    float Dv = __fmul_rn(m2, __fsqrt_rn(s));
    D[e] = Dv;
    lmax = fmaxf(lmax, Dv);
  }
  #pragma unroll
  for (int off = 32; off > 0; off >>= 1) lmax = fmaxf(lmax, __shfl_xor(lmax, off, 64));
  unsigned long long key[8];
  unsigned long long lmin = ~0ull;
  #pragma unroll
  for (int e = 0; e < 8; e++) {
    int j = l * 8 + e;
    float m2 = __fmul_rn(mi, ms[j]);
    float d = __fadd_rn(D[e], __fmul_rn(__fsub_rn(1.f, m2), lmax));
    unsigned long long k = (((unsigned long long)__float_as_uint(d)) << 32)
                         | (unsigned)(N_ - 1 - j);
    key[e] = k;
    if (k < lmin) lmin = k;
  }
  for (int kk = 0; kk < K_; kk++) {
    unsigned long long m = lmin;
    #pragma unroll
    for (int off = 32; off > 0; off >>= 1) {
      unsigned long long o = __shfl_xor(m, off, 64);
      if (o < m) m = o;
    }
    int j = N_ - 1 - (int)(m & 0xffffffffull);
    if (l == 0) {
      E_idx[(size_t)(b * N_ + i) * K_ + kk] = j;
      Dnb[(size_t)(b * N_ + i) * K_ + kk] = __uint_as_float((unsigned)(m >> 32));
    }
    if ((j >> 3) == l) {
      key[j & 7] = ~0ull;
      unsigned long long nm = key[0];
      #pragma unroll
      for (int e = 1; e < 8; e++) if (key[e] < nm) nm = key[e];
      lmin = nm;
    }
  }
}

// ---------------- dihedral features (1 thread / node), fp32 ----------------
DEVFN void load_atom(const float* X, int b, int m, float* p) {
  const float* q = X + ((size_t)(b * N_ + m / 3) * 4 + (m % 3)) * 3;
  p[0] = q[0]; p[1] = q[1]; p[2] = q[2];
}
DEVFN void cross3(const float* a, const float* b, float* c) {
  c[0] = a[1] * b[2] - a[2] * b[1];
  c[1] = a[2] * b[0] - a[0] * b[2];
  c[2] = a[0] * b[1] - a[1] * b[0];
}
DEVFN void norm3(float* v) {
  float n = sqrtf(v[0] * v[0] + v[1] * v[1] + v[2] * v[2]) + 1e-7f;
  v[0] /= n; v[1] /= n; v[2] /= n;
}
__global__ __launch_bounds__(256) void dihedral_kernel(const float* __restrict__ X, float* __restrict__ Vf) {
  int idx = blockIdx.x * blockDim.x + threadIdx.x;
  if (idx >= BN_) return;
  int b = idx / N_, n = idx % N_;
  float cs[3], sn[3];
  for (int s = 0; s < 3; s++) {
    int p = 3 * n + s;
    float a = 0.f;
    if (p >= 1 && p <= 3 * N_ - 3) {
      int tt = p - 1;
      float u[3][3], prev[3], cur[3];
      load_atom(X, b, tt, prev);
      for (int q = 0; q < 3; q++) {
        load_atom(X, b, tt + q + 1, cur);
        float d0 = cur[0] - prev[0], d1 = cur[1] - prev[1], d2 = cur[2] - prev[2];
        float nr = sqrtf(d0 * d0 + d1 * d1 + d2 * d2) + 1e-7f;
        u[q][0] = d0 / nr; u[q][1] = d1 / nr; u[q][2] = d2 / nr;
        prev[0] = cur[0]; prev[1] = cur[1]; prev[2] = cur[2];
      }
      float n2v[3], n1v[3];
      cross3(u[0], u[1], n2v); norm3(n2v);
      cross3(u[1], u[2], n1v); norm3(n1v);
      float cd = n2v[0] * n1v[0] + n2v[1] * n1v[1] + n2v[2] * n1v[2];
      cd = fminf(fmaxf(cd, -1.f + 1e-7f), 1.f - 1e-7f);
      float dt = u[0][0] * n1v[0] + u[0][1] * n1v[1] + u[0][2] * n1v[2];
      float sg = (dt > 0.f) ? 1.f : ((dt < 0.f) ? -1.f : 0.f);
      a = sg * acosf(cd);
    }
    cs[s] = cosf(a); sn[s] = sinf(a);
  }
  float* o = Vf + (size_t)idx * 6;
  o[0] = cs[0]; o[1] = cs[1]; o[2] = cs[2]; o[3] = sn[0]; o[4] = sn[1]; o[5] = sn[2];
}

// ---------------- node embed: hV = LN(V@Wfn+bfn) @ Wv + bv (fp32, shuffle-LN) ----------------
__global__ __launch_bounds__(H_) void node_embed_kernel(const float* __restrict__ Vf,
    const float* __restrict__ Wfn, const float* __restrict__ bfn,
    const float* __restrict__ Wv, const float* __restrict__ bv, float* __restrict__ hV) {
  int node = blockIdx.x, t = threadIdx.x;
  const int w = t >> 6, l = t & 63;
  __shared__ float v6[6];
  __shared__ __attribute__((aligned(16))) float t1[H_];
  __shared__ float wred[2];
  if (t < 6) v6[t] = Vf[(size_t)node * 6 + t];
  __syncthreads();
  float acc = bfn[t];
  for (int f = 0; f < 6; f++) acc = fmaf(v6[f], Wfn[f * H_ + t], acc);
  float s1 = acc;
  #pragma unroll
  for (int off = 32; off > 0; off >>= 1) s1 += __shfl_xor(s1, off, 64);
  if (l == 0) wred[w] = s1;
  __syncthreads();
  float mean = (wred[0] + wred[1]) * (1.f / H_);
  float d0 = acc - mean;
  float s2 = d0 * d0;
  #pragma unroll
  for (int off = 32; off > 0; off >>= 1) s2 += __shfl_xor(s2, off, 64);
  __syncthreads();
  if (l == 0) wred[w] = s2;
  __syncthreads();
  float var = (wred[0] + wred[1]) * (1.f / H_);
  t1[t] = d0 * rsqrtf(var + 1e-6f);
  __syncthreads();
  float o = bv[t];
  for (int j4 = 0; j4 < H_ / 4; j4++) {
    float4 xv = ((const float4*)t1)[j4];
    int j = j4 * 4;
    o = fmaf(xv.x, Wv[(j + 0) * H_ + t],
        fmaf(xv.y, Wv[(j + 1) * H_ + t],
        fmaf(xv.z, Wv[(j + 2) * H_ + t],
        fmaf(xv.w, Wv[(j + 3) * H_ + t], o))));
  }
  hV[(size_t)node * H_ + t] = o;
}

// ---------------- prep Wfe (32x128) + We (128x128) -> MFMA B-frag bf16 hi/lo ----------------
__global__ __launch_bounds__(256) void prep_edge_w_kernel(const float* __restrict__ Wfe,
    const float* __restrict__ We, ushort_t* __restrict__ feHi, ushort_t* __restrict__ feLo,
    ushort_t* __restrict__ weHi, ushort_t* __restrict__ weLo) {
  if (blockIdx.x == 0) {
    for (int i = 0; i < 4096 / 256; i++) {
      int lin = i * 256 + threadIdx.x;   // k*128 + c, k<32
      int k = lin >> 7, c = lin & 127;
      float x = Wfe[lin];
      int gk = k >> 3, j = k & 7;
      int nt = c >> 4, cc = c & 15;
      int oidx = (nt * 64 + gk * 16 + cc) * 8 + j;
      ushort_t hb = bf16rn(x);
      feHi[oidx] = hb;
      feLo[oidx] = bf16rn(x - bf16tof(hb));
    }
  } else {
    for (int i = 0; i < FRAG_ / 256; i++) {
      int lin = i * 256 + threadIdx.x;
      int k = lin >> 7, c = lin & 127;
      float x = We[lin];
      int ks = k >> 5, gk = (k >> 3) & 3, j = k & 7;
      int nt = c >> 4, cc = c & 15;
      int oidx = ((ks * 8 + nt) * 64 + gk * 16 + cc) * 8 + j;
      ushort_t hb = bf16rn(x);
      weHi[oidx] = hb;
      weLo[oidx] = bf16rn(x - bf16tof(hb));
    }
  }
}

// ---------------- prep WK1T: transpose first HxH block of attn K-weights (fp32) ----------------
__global__ __launch_bounds__(256) void prep_wkt_kernel(const float* __restrict__ eWK,
    const float* __restrict__ dWK, float* __restrict__ outT) {
  int m = blockIdx.x;  // 0..2 enc, 3..5 dec
  const float* W = (m < 3) ? (eWK + (size_t)m * 2 * H_ * H_)
                           : (dWK + (size_t)(m - 3) * 3 * H_ * H_);
  float* o = outT + (size_t)m * FRAG_;
  for (int i = 0; i < FRAG_ / 256; i++) {
    int lin = i * 256 + threadIdx.x;   // lin = c*H + f (coalesced write)
    int c = lin >> 7, f = lin & 127;
    o[lin] = W[f * H_ + c];
  }
}

// ---------------- edge embed via split-bf16 MFMA: hE = LN(E@Wfe+bfe) @ We + be ----------------
constexpr int EEB_ = 32;
constexpr int FPS_ = 40;   // feats plane stride in shorts
__global__ __launch_bounds__(128) void edge_embed_kernel(const int* __restrict__ E_idx,
    const float* __restrict__ Dnb,
    const ushort_t* __restrict__ feHi, const ushort_t* __restrict__ feLo,
    const float* __restrict__ bfe,
    const ushort_t* __restrict__ weHi, const ushort_t* __restrict__ weLo,
    const float* __restrict__ be, float* __restrict__ hE) {
  int e0 = blockIdx.x * EEB_, t = threadIdx.x;
  const int w = t >> 6, l = t & 63, c0 = l & 15, g = l >> 4;
  __shared__ ushort_t fhi[EEB_ * FPS_], flo[EEB_ * FPS_];
  __shared__ __attribute__((aligned(16))) char sbuf[EEB_ * H_ * 4];
  float* buf = (float*)sbuf;
  ushort_t* p2hi = (ushort_t*)sbuf;
  ushort_t* p2lo = (ushort_t*)(sbuf + EEB_ * H_ * 2);
  __shared__ float mst[EEB_], ist[EEB_];

  #pragma unroll
  for (int it = 0; it < 8; it++) {
    int id = it * 128 + t;
    int r = id >> 5, f = id & 31;
    int e = e0 + r;
    int n = (e / K_) % N_;
    float v;
    if (f < 16) {
      int jj = (f < 8) ? f : (f - 8);
      float freq = expf(-logf(10000.f) * (2.f * jj) / 16.f);
      float ang = (float)(E_idx[e] - n) * freq;
      v = (f < 8) ? cosf(ang) : sinf(ang);
    } else {
      int rr = f - 16;
      float mu = 20.f * (float)rr / 15.f;
      float z = (Dnb[e] - mu) * (1.f / 1.25f);
      v = expf(-z * z);
    }
    ushort_t hb = bf16rn(v);
    fhi[r * FPS_ + f] = hb;
    flo[r * FPS_ + f] = bf16rn(v - bf16tof(hb));
  }
  __syncthreads();

  {
    short8 ah[2], al[2];
    #pragma unroll
    for (int mt = 0; mt < 2; mt++) {
      int r = mt * 16 + c0;
      ah[mt] = *(const short8*)&fhi[r * FPS_ + g * 8];
      al[mt] = *(const short8*)&flo[r * FPS_ + g * 8];
    }
    #pragma unroll
    for (int nt = 0; nt < 4; nt++) {
      int ntg = w * 4 + nt;
      size_t boff = (size_t)((ntg * 64 + l) * 8);
      short8 bh = *(const short8*)(feHi + boff);
      short8 bl = *(const short8*)(feLo + boff);
      int c = ntg * 16 + c0;
      float bb = bfe[c];
      #pragma unroll
      for (int mt = 0; mt < 2; mt++) {
        f32x4 a = f32x4{0.f, 0.f, 0.f, 0.f};
        a = __builtin_amdgcn_mfma_f32_16x16x32_bf16(ah[mt], bh, a, 0, 0, 0);
        a = __builtin_amdgcn_mfma_f32_16x16x32_bf16(al[mt], bh, a, 0, 0, 0);
        a = __builtin_amdgcn_mfma_f32_16x16x32_bf16(ah[mt], bl, a, 0, 0, 0);
        a = __builtin_amdgcn_mfma_f32_16x16x32_bf16(al[mt], bl, a, 0, 0, 0);
        #pragma unroll
        for (int j = 0; j < 4; j++) {
          int row = mt * 16 + g * 4 + j;
          buf[row * H_ + c] = a[j] + bb;
        }
      }
    }
  }
  __syncthreads();

  {
    int row = t >> 2, li = t & 3;
    float s = 0.f;
    for (int i = 0; i < 32; i++) {
      int col = li + 4 * ((i + row) & 31);
      s += buf[row * H_ + col];
    }
    s += __shfl_xor(s, 1, 64); s += __shfl_xor(s, 2, 64);
    float mean = s * (1.f / H_);
    float vs = 0.f;
    for (int i = 0; i < 32; i++) {
      int col = li + 4 * ((i + row) & 31);
      float d = buf[row * H_ + col] - mean;
      vs = fmaf(d, d, vs);
    }
    vs += __shfl_xor(vs, 1, 64); vs += __shfl_xor(vs, 2, 64);
    if (li == 0) { mst[row] = mean; ist[row] = rsqrtf(vs * (1.f / H_) + 1e-6f); }
  }
  __syncthreads();

  float vreg[32];
  #pragma unroll
  for (int it = 0; it < 4; it++) {
    int id = it * 128 + t;
    int r = id >> 4, u = id & 15;
    float mean = mst[r], inv = ist[r];
    #pragma unroll
    for (int e2 = 0; e2 < 8; e2++) vreg[it * 8 + e2] = (buf[r * H_ + u * 8 + e2] - mean) * inv;
  }
  __syncthreads();
  #pragma unroll
  for (int it = 0; it < 4; it++) {
    int id = it * 128 + t;
    int r = id >> 4, u = id & 15;
    short8 h8, l8;
    #pragma unroll
    for (int e2 = 0; e2 < 8; e2++) {
      float x = vreg[it * 8 + e2];
      ushort_t hb = bf16rn(x);
      h8[e2] = (short)hb;
      l8[e2] = (short)bf16rn(x - bf16tof(hb));
    }
    int us = u ^ (r & 15);
    *(short8*)&p2hi[r * 128 + us * 8] = h8;
    *(short8*)&p2lo[r * 128 + us * 8] = l8;
  }
  __syncthreads();

  short8 ah2[2][4], al2[2][4];
  #pragma unroll
  for (int mt = 0; mt < 2; mt++) {
    int r = mt * 16 + c0;
    #pragma unroll
    for (int ks = 0; ks < 4; ks++) {
      int us = (ks * 4 + g) ^ c0;
      ah2[mt][ks] = *(const short8*)&p2hi[r * 128 + us * 8];
      al2[mt][ks] = *(const short8*)&p2lo[r * 128 + us * 8];
    }
  }
  f32x4 acc2[2][4];
  #pragma unroll
  for (int mt = 0; mt < 2; mt++)
    #pragma unroll
    for (int nt = 0; nt < 4; nt++) acc2[mt][nt] = f32x4{0.f, 0.f, 0.f, 0.f};
  #pragma unroll
  for (int ks = 0; ks < 4; ks++) {
    #pragma unroll
    for (int nt = 0; nt < 4; nt++) {
      int ntg = w * 4 + nt;
      size_t boff = (size_t)(((ks * 8 + ntg) * 64 + l) * 8);
      short8 bh = *(const short8*)(weHi + boff);
      short8 bl = *(const short8*)(weLo + boff);
      #pragma unroll
      for (int mt = 0; mt < 2; mt++) {
        acc2[mt][nt] = __builtin_amdgcn_mfma_f32_16x16x32_bf16(ah2[mt][ks], bh, acc2[mt][nt], 0, 0, 0);
        acc2[mt][nt] = __builtin_amdgcn_mfma_f32_16x16x32_bf16(al2[mt][ks], bh, acc2[mt][nt], 0, 0, 0);
        acc2[mt][nt] = __builtin_amdgcn_mfma_f32_16x16x32_bf16(ah2[mt][ks], bl, acc2[mt][nt], 0, 0, 0);
        acc2[mt][nt] = __builtin_amdgcn_mfma_f32_16x16x32_bf16(al2[mt][ks], bl, acc2[mt][nt], 0, 0, 0);
      }
    }
  }
  #pragma unroll
  for (int mt = 0; mt < 2; mt++) {
    #pragma unroll
    for (int nt = 0; nt < 4; nt++) {
      int c = (w * 4 + nt) * 16 + c0;
      float bb = be[c];
      #pragma unroll
      for (int j = 0; j < 4; j++) {
        int row = mt * 16 + g * 4 + j;
        hE[(size_t)(e0 + row) * H_ + c] = acc2[mt][nt][j] + bb;
      }
    }
  }
}

// ---------------- per-node projection (encoder): oa/ob = x@Wa/Wb ----------------
__global__ __launch_bounds__(128) void node_proj_kernel(const float* __restrict__ x1,
    const float* __restrict__ Wa1, const float* __restrict__ Wb1,
    float* __restrict__ oa, float* __restrict__ ob) {
  constexpr int NT = 16;
  int n0 = blockIdx.x * NT, t = threadIdx.x;
  __shared__ __attribute__((aligned(16))) float xs1[NT * H_];
  #pragma unroll
  for (int u = 0; u < NT; u++) xs1[u * H_ + t] = x1[(size_t)(n0 + u) * H_ + t];
  __syncthreads();
  float aa[NT], ab[NT];
  #pragma unroll
  for (int u = 0; u < NT; u++) { aa[u] = 0.f; ab[u] = 0.f; }
  for (int j4 = 0; j4 < H_ / 4; j4++) {
    int j = j4 * 4;
    float wa0 = Wa1[(j + 0) * H_ + t], wa1 = Wa1[(j + 1) * H_ + t];
    float wa2 = Wa1[(j + 2) * H_ + t], wa3 = Wa1[(j + 3) * H_ + t];
    float wb0 = Wb1[(j + 0) * H_ + t], wb1 = Wb1[(j + 1) * H_ + t];
    float wb2 = Wb1[(j + 2) * H_ + t], wb3 = Wb1[(j + 3) * H_ + t];
    #pragma unroll
    for (int u = 0; u < NT; u++) {
      float4 xv = ((const float4*)(xs1 + u * H_))[j4];
      aa[u] = fmaf(xv.x, wa0, fmaf(xv.y, wa1, fmaf(xv.z, wa2, fmaf(xv.w, wa3, aa[u]))));
      ab[u] = fmaf(xv.x, wb0, fmaf(xv.y, wb1, fmaf(xv.z, wb2, fmaf(xv.w, wb3, ab[u]))));
    }
  }
  #pragma unroll
  for (int u = 0; u < NT; u++) {
    oa[(size_t)(n0 + u) * H_ + t] = aa[u];
    ob[(size_t)(n0 + u) * H_ + t] = ab[u];
  }
}

// ---------------- decoder fused projection ----------------
__global__ __launch_bounds__(128) void node_proj3_kernel(const int* __restrict__ S,
    const float* __restrict__ Ws, const float* __restrict__ din, const float* __restrict__ henc,
    const float* __restrict__ WK2, const float* __restrict__ WV2,
    const float* __restrict__ WK3, const float* __restrict__ WV3,
    float* __restrict__ nKb, float* __restrict__ nVb,
    float* __restrict__ nKe, float* __restrict__ nVe) {
  constexpr int NT = 8;
  int n0 = blockIdx.x * NT, t = threadIdx.x;
  __shared__ __attribute__((aligned(16))) float xs1[NT * H_];  // hS
  __shared__ __attribute__((aligned(16))) float xs2[NT * H_];  // din
  __shared__ __attribute__((aligned(16))) float xs3[NT * H_];  // henc
  #pragma unroll
  for (int u = 0; u < NT; u++) {
    int node = n0 + u;
    xs1[u * H_ + t] = Ws[(size_t)S[node] * H_ + t];
    xs2[u * H_ + t] = din[(size_t)node * H_ + t];
    xs3[u * H_ + t] = henc[(size_t)node * H_ + t];
  }
  __syncthreads();
  float aKb[NT], aVb[NT], aKe[NT], aVe[NT];
  #pragma unroll
  for (int u = 0; u < NT; u++) { aKb[u] = 0.f; aVb[u] = 0.f; aKe[u] = 0.f; aVe[u] = 0.f; }
  for (int j4 = 0; j4 < H_ / 4; j4++) {
    int j = j4 * 4;
    float k20 = WK2[(j + 0) * H_ + t], k21 = WK2[(j + 1) * H_ + t];
    float k22 = WK2[(j + 2) * H_ + t], k23 = WK2[(j + 3) * H_ + t];
    float v20 = WV2[(j + 0) * H_ + t], v21 = WV2[(j + 1) * H_ + t];
    float v22 = WV2[(j + 2) * H_ + t], v23 = WV2[(j + 3) * H_ + t];
    float k30 = WK3[(j + 0) * H_ + t], k31 = WK3[(j + 1) * H_ + t];
    float k32 = WK3[(j + 2) * H_ + t], k33 = WK3[(j + 3) * H_ + t];
    float v30 = WV3[(j + 0) * H_ + t], v31 = WV3[(j + 1) * H_ + t];
    float v32 = WV3[(j + 2) * H_ + t], v33 = WV3[(j + 3) * H_ + t];
    #pragma unroll
    for (int u = 0; u < NT; u++) {
      float4 a = ((const float4*)(xs1 + u * H_))[j4];
      float4 b = ((const float4*)(xs2 + u * H_))[j4];
      float4 c = ((const float4*)(xs3 + u * H_))[j4];
      aKb[u] = fmaf(a.x, k20, fmaf(a.y, k21, fmaf(a.z, k22, fmaf(a.w, k23, aKb[u]))));
      aKb[u] = fmaf(b.x, k30, fmaf(b.y, k31, fmaf(b.z, k32, fmaf(b.w, k33, aKb[u]))));
      aVb[u] = fmaf(a.x, v20, fmaf(a.y, v21, fmaf(a.z, v22, fmaf(a.w, v23, aVb[u]))));
      aVb[u] = fmaf(b.x, v30, fmaf(b.y, v31, fmaf(b.z, v32, fmaf(b.w, v33, aVb[u]))));
      aKe[u] = fmaf(c.x, k30, fmaf(c.y, k31, fmaf(c.z, k32, fmaf(c.w, k33, aKe[u]))));
      aVe[u] = fmaf(c.x, v30, fmaf(c.y, v31, fmaf(c.z, v32, fmaf(c.w, v33, aVe[u]))));
    }
  }
  #pragma unroll
  for (int u = 0; u < NT; u++) {
    size_t g = (size_t)(n0 + u) * H_ + t;
    nKb[g] = aKb[u]; nVb[g] = aVb[u]; nKe[g] = aKe[u]; nVe[g] = aVe[u];
  }
}

// ---------------- weight-fragment prep for FFN W1 (128x512) / W2 (512x128) ----------------
__global__ __launch_bounds__(256) void prep_wfrag2_kernel(const float* __restrict__ eW1,
    const float* __restrict__ eW2, const float* __restrict__ dW1, const float* __restrict__ dW2,
    ushort_t* __restrict__ hiOut, ushort_t* __restrict__ loOut) {
  int m = blockIdx.x;  // 0..11: eW1 l0-2, eW2 l0-2, dW1 l0-2, dW2 l0-2
  const float* W; int C;
  if (m < 3)      { W = eW1 + (size_t)m * FRAG2_;       C = 4 * H_; }
  else if (m < 6) { W = eW2 + (size_t)(m - 3) * FRAG2_; C = H_; }
  else if (m < 9) { W = dW1 + (size_t)(m - 6) * FRAG2_; C = 4 * H_; }
  else            { W = dW2 + (size_t)(m - 9) * FRAG2_; C = H_; }
  ushort_t* hi = hiOut + (size_t)m * FRAG2_;
  ushort_t* lo = loOut + (size_t)m * FRAG2_;
  int ntn = C >> 4;
  int cshift = (C == 512) ? 9 : 7;
  for (int i = 0; i < FRAG2_ / 256; i++) {
    int lin = i * 256 + threadIdx.x;
    int k = lin >> cshift, c = lin & (C - 1);
    float x = W[lin];
    int ks = k >> 5, gk = (k >> 3) & 3, j = k & 7;
    int nt = c >> 4, cc = c & 15;
    int lane = gk * 16 + cc;
    int oidx = ((ks * ntn + nt) * 64 + lane) * 8 + j;
    ushort_t hb = bf16rn(x);
    hi[oidx] = hb;
    lo[oidx] = bf16rn(x - bf16tof(hb));
  }
}

// ---------------- fused graph attention + residual LN — 8 nodes/block + LDS tile pipeline ----------------
// R11: weight streams amortized over 8 nodes. R12: per-node pipeline (helped via MLP but
// FETCH stayed 290MB — L2 evicts the tile even across the softmax window). R13: stage each
// node's 15KB hE tile in LDS inside the pipeline -> tile read from HBM exactly once
// (R7-proven mechanism, now combined with weight amortization). Values copied exactly;
// all per-node summation orders unchanged -> bit-identical output.
constexpr int ANT_ = 8;
template<bool ENC>
__global__ __launch_bounds__(128) void attn_kernel(const float* __restrict__ hV_in,
    const float* __restrict__ hE, const int* __restrict__ E_idx, const float* __restrict__ mask,
    const float* __restrict__ WQ, const float* __restrict__ WK1T, const float* __restrict__ WV1,
    const float* __restrict__ WO,
    const float* __restrict__ nKb, const float* __restrict__ nVb,
    const float* __restrict__ nKe, const float* __restrict__ nVe,
    float* __restrict__ hV_out) {
  const int node0 = blockIdx.x * ANT_;
  const int b = node0 / N_;
  const int nbase = node0 % N_;          // all 8 nodes share batch b (N_ % ANT_ == 0)
  const int t = threadIdx.x;
  const int g = t >> 5, lane32 = t & 31;
  const int head = g;

  __shared__ __attribute__((aligned(16))) float heb[K_ * H_];        // one node's hE tile
  __shared__ __attribute__((aligned(16))) float x0s[ANT_][H_];
  __shared__ __attribute__((aligned(16))) float qs[ANT_][H_];        // q, later ob
  __shared__ __attribute__((aligned(16))) float qkagg[ANT_][4 * H_]; // qk, later agg
  __shared__ float scb[ANT_][NH_ * 32];                              // scores/att, later r
  __shared__ int nbs[ANT_][K_];
  __shared__ float mis[ANT_];
  __shared__ float mst[ANT_], ist[ANT_];

  // stage x0, neighbor lists, masks; pad score slots
  #pragma unroll
  for (int u = 0; u < ANT_; u++) {
    x0s[u][t] = hV_in[(size_t)(node0 + u) * H_ + t];
    if ((t & 31) >= K_) scb[u][t] = NEG_INF_;
  }
  for (int i = t; i < ANT_ * K_; i += 128) nbs[i / K_][i % K_] = E_idx[(size_t)node0 * K_ + i];
  if (t < ANT_) mis[t] = mask[(size_t)b * N_ + nbase + t];
  __syncthreads();

  // q = x0 @ WQ  (weights read once per block; per-node fmaf order = R7)
  {
    float qv[ANT_];
    #pragma unroll
    for (int u = 0; u < ANT_; u++) qv[u] = 0.f;
    for (int j4 = 0; j4 < H_ / 4; j4++) {
      int j = j4 * 4;
      float w0 = WQ[(j + 0) * H_ + t], w1 = WQ[(j + 1) * H_ + t];
      float w2 = WQ[(j + 2) * H_ + t], w3 = WQ[(j + 3) * H_ + t];
      #pragma unroll
      for (int u = 0; u < ANT_; u++) {
        float4 xv = ((const float4*)x0s[u])[j4];
        qv[u] = fmaf(xv.x, w0, fmaf(xv.y, w1, fmaf(xv.z, w2, fmaf(xv.w, w3, qv[u]))));
      }
    }
    #pragma unroll
    for (int u = 0; u < ANT_; u++) qs[u][t] = qv[u];
  }
  __syncthreads();

  // qk[h][t] = sum_{c in head h} WK1T[c*H+t] * q[c]  (per-node order = R7)
  {
    float ak[ANT_][4];
    #pragma unroll
    for (int u = 0; u < ANT_; u++)
      #pragma unroll
      for (int h = 0; h < 4; h++) ak[u][h] = 0.f;
    for (int c = 0; c < 32; c++) {
      float wA = WK1T[(c      ) * H_ + t];
      float wB = WK1T[(c + 32 ) * H_ + t];
      float wC = WK1T[(c + 64 ) * H_ + t];
      float wD = WK1T[(c + 96 ) * H_ + t];
      #pragma unroll
      for (int u = 0; u < ANT_; u++) {
        ak[u][0] = fmaf(wA, qs[u][c      ], ak[u][0]);
        ak[u][1] = fmaf(wB, qs[u][c + 32 ], ak[u][1]);
        ak[u][2] = fmaf(wC, qs[u][c + 64 ], ak[u][2]);
        ak[u][3] = fmaf(wD, qs[u][c + 96 ], ak[u][3]);
      }
    }
    #pragma unroll
    for (int u = 0; u < ANT_; u++)
      #pragma unroll
      for (int h = 0; h < 4; h++) qkagg[u][h * H_ + t] = ak[u][h];
  }
  __syncthreads();

  // per-node pipeline: stage_u -> scores_u -> softmax_u -> agg_u + onode_u
  float onode[ANT_];
  const float scale = 0.17677669529663687f;  // 1/sqrt(32)
  #pragma unroll 1
  for (int u = 0; u < ANT_; u++) {
    const float mi = mis[u];
    const int nmod = nbase + u;
    // ---- stage_u: one global read of node u's tile into LDS
    {
      const float4* src = (const float4*)(hE + (size_t)(node0 + u) * (K_ * H_));
      float4* dst = (float4*)heb;
      #pragma unroll
      for (int i = 0; i < (K_ * H_ / 4 + 127) / 128; i++) {
        int id = i * 128 + t;
        if (id < K_ * H_ / 4) dst[id] = src[id];
      }
    }
    __syncthreads();
    // ---- scores_u: group g handles edges k = g, g+4, ...; per-edge math/butterfly = R7
    {
      float qkv[4][4];
      #pragma unroll
      for (int h = 0; h < 4; h++)
        #pragma unroll
        for (int j = 0; j < 4; j++)
          qkv[h][j] = qkagg[u][h * H_ + lane32 + 32 * j];
      float qv[4];
      #pragma unroll
      for (int h = 0; h < 4; h++) qv[h] = qs[u][lane32 + 32 * h];
      #pragma unroll 1
      for (int kk = 0; kk < 8; kk++) {
        int k = g + 4 * kk;
        if (k >= K_) break;
        int nb = nbs[u][k];
        size_t nbg = (size_t)(b * N_ + nb) * H_ + lane32;
        float gbv[4], gev[4], m2;
        gbv[0] = nKb[nbg]; gbv[1] = nKb[nbg + 32]; gbv[2] = nKb[nbg + 64]; gbv[3] = nKb[nbg + 96];
        if (!ENC) {
          gev[0] = nKe[nbg]; gev[1] = nKe[nbg + 32]; gev[2] = nKe[nbg + 64]; gev[3] = nKe[nbg + 96];
        } else {
          m2 = mi * mask[b * N_ + nb];
        }
        const float* he = heb + k * H_;
        float he0 = he[lane32], he1 = he[lane32 + 32], he2 = he[lane32 + 64], he3 = he[lane32 + 96];
        float pr[4];
        #pragma unroll
        for (int h = 0; h < 4; h++) {
          float ep = fmaf(qkv[h][0], he0,
                     fmaf(qkv[h][1], he1,
                     fmaf(qkv[h][2], he2, qkv[h][3] * he3)));
          if (ENC) {
            pr[h] = fmaf(qv[h], gbv[h], ep);
          } else {
            float ar = (nb < nmod) ? 1.f : 0.f;
            float bw = mi * ar, fw = mi * (1.f - ar);
            float nodek = fmaf(bw, gbv[h], fw * gev[h]);
            pr[h] = fmaf(mi, ep, qv[h] * nodek);
          }
        }
        #pragma unroll
        for (int off = 16; off > 0; off >>= 1)
          #pragma unroll
          for (int h = 0; h < 4; h++)
            pr[h] += __shfl_xor(pr[h], off, 32);
        if (lane32 == 0) {
          #pragma unroll
          for (int h = 0; h < 4; h++) {
            if (ENC) scb[u][h * 32 + k] = (m2 > 0.f) ? pr[h] * scale : NEG_INF_;
            else     scb[u][h * 32 + k] = pr[h] * scale;
          }
        }
      }
    }
    __syncthreads();
    // ---- softmax_u (= R7 per node)
    {
      float s = scb[u][t];
      float mx = s;
      #pragma unroll
      for (int off = 16; off > 0; off >>= 1) mx = fmaxf(mx, __shfl_xor(mx, off, 32));
      float ev = expf(s - mx);
      float sum = ev;
      #pragma unroll
      for (int off = 16; off > 0; off >>= 1) sum += __shfl_xor(sum, off, 32);
      scb[u][t] = ev / sum;
    }
    __syncthreads();
    // ---- agg_u: reads the LDS tile; k order = R7
    {
      float a0 = 0.f, a1 = 0.f, a2 = 0.f, a3 = 0.f;
      #pragma unroll
      for (int k = 0; k < K_; k++) {
        float hv = heb[k * H_ + t];
        a0 = fmaf(scb[u][0 * 32 + k], hv, a0);
        a1 = fmaf(scb[u][1 * 32 + k], hv, a1);
        a2 = fmaf(scb[u][2 * 32 + k], hv, a2);
        a3 = fmaf(scb[u][3 * 32 + k], hv, a3);
      }
      qkagg[u][0 * H_ + t] = a0;
      qkagg[u][1 * H_ + t] = a1;
      qkagg[u][2 * H_ + t] = a2;
      qkagg[u][3 * H_ + t] = a3;
    }
    // ---- onode_u with KT=10 batching (= R7)
    {
      float on = 0.f;
      for (int kt = 0; kt < K_; kt += 10) {
        float gv[10], gve[10];
        #pragma unroll
        for (int i = 0; i < 10; i++) {
          int nb = nbs[u][kt + i];
          size_t nbg = (size_t)(b * N_ + nb) * H_ + t;
          gv[i] = nVb[nbg];
          if (!ENC) gve[i] = nVe[nbg];
        }
        #pragma unroll
        for (int i = 0; i < 10; i++) {
          int k = kt + i;
          float att = scb[u][head * 32 + k];
          if (ENC) {
            on = fmaf(att, gv[i], on);
          } else {
            int nb = nbs[u][k];
            float ar = (nb < nmod) ? 1.f : 0.f;
            float bw = mi * ar, fw = mi * (1.f - ar);
            on = fmaf(att, fmaf(bw, gv[i], fw * gve[i]), on);
          }
        }
      }
      onode[u] = on;
    }
    __syncthreads();  // heb + scb[u] safe before next stage_u
  }

  // oe[t] = agg_{head} @ WV1[:, t]  (weights once per block; f order = R7)
  float oreg[ANT_];
  {
    float oe[ANT_];
    #pragma unroll
    for (int u = 0; u < ANT_; u++) oe[u] = 0.f;
    for (int f = 0; f < H_; f++) {
      float wv = WV1[f * H_ + t];
      #pragma unroll
      for (int u = 0; u < ANT_; u++)
        oe[u] = fmaf(qkagg[u][head * H_ + f], wv, oe[u]);
    }
    #pragma unroll
    for (int u = 0; u < ANT_; u++)
      oreg[u] = ENC ? (oe[u] + onode[u]) : fmaf(mis[u], oe[u], onode[u]);
  }
  #pragma unroll
  for (int u = 0; u < ANT_; u++) qs[u][t] = oreg[u];   // ob (qs dead after scores)
  __syncthreads();

  // dh = ob @ WO (weights once per block; j4 order = R7); residual
  float rv[ANT_];
  {
    float dh[ANT_];
    #pragma unroll
    for (int u = 0; u < ANT_; u++) dh[u] = 0.f;
    for (int j4 = 0; j4 < H_ / 4; j4++) {
      int j = j4 * 4;
      float w0 = WO[(j + 0) * H_ + t], w1 = WO[(j + 1) * H_ + t];
      float w2 = WO[(j + 2) * H_ + t], w3 = WO[(j + 3) * H_ + t];
      #pragma unroll
      for (int u = 0; u < ANT_; u++) {
        float4 ov = ((const float4*)qs[u])[j4];
        dh[u] = fmaf(ov.x, w0, fmaf(ov.y, w1, fmaf(ov.z, w2, fmaf(ov.w, w3, dh[u]))));
      }
    }
    #pragma unroll
    for (int u = 0; u < ANT_; u++) rv[u] = x0s[u][t] + dh[u];
  }
  #pragma unroll
  for (int u = 0; u < ANT_; u++) scb[u][t] = rv[u];    // r rows (scb dead after onode)
  __syncthreads();

  // row LN stats: 16 threads per node-row (ffn-style)
  {
    int u = t >> 4, li = t & 15;
    float s = 0.f;
    #pragma unroll
    for (int i = 0; i < 8; i++) s += scb[u][li + 16 * i];
    s += __shfl_xor(s, 1, 64); s += __shfl_xor(s, 2, 64);
    s += __shfl_xor(s, 4, 64); s += __shfl_xor(s, 8, 64);
    float mean = s * (1.f / H_);
    float vs = 0.f;
    #pragma unroll
    for (int i = 0; i < 8; i++) {
      float d = scb[u][li + 16 * i] - mean;
      vs = fmaf(d, d, vs);
    }
    vs += __shfl_xor(vs, 1, 64); vs += __shfl_xor(vs, 2, 64);
    vs += __shfl_xor(vs, 4, 64); vs += __shfl_xor(vs, 8, 64);
    if (li == 0) { mst[u] = mean; ist[u] = rsqrtf(vs * (1.f / H_) + 1e-6f); }
  }
  __syncthreads();
  #pragma unroll
  for (int u = 0; u < ANT_; u++)
    hV_out[(size_t)(node0 + u) * H_ + t] = (rv[u] - mst[u]) * ist[u];
}

// ---------------- FFN via split-bf16 MFMA: LN(x + relu(x@W1+b1)@W2+b2) * mask ----------------
constexpr int NTF_ = 8;
__global__ __launch_bounds__(128) void ffn_kernel(float* __restrict__ hV, const float* __restrict__ mask,
    const ushort_t* __restrict__ w1hi, const ushort_t* __restrict__ w1lo,
    const ushort_t* __restrict__ w2hi, const ushort_t* __restrict__ w2lo,
    const float* __restrict__ b1, const float* __restrict__ b2) {
  int n0 = blockIdx.x * NTF_, t = threadIdx.x;
  const int w = t >> 6, l = t & 63, c0 = l & 15, g = l >> 4;
  __shared__ __attribute__((aligned(16))) ushort_t xhi[16 * H_], xlo[16 * H_];
  __shared__ __attribute__((aligned(16))) ushort_t hpl[2][2 * 16 * H_];
  __shared__ float mst[16], ist[16];
  float* obuf = (float*)&hpl[0][0];

  #pragma unroll
  for (int it = 0; it < 2; it++) {
    int id = it * 128 + t;
    int r = id >> 4, u = id & 15;
    short8 h8 = {0,0,0,0,0,0,0,0}, l8 = {0,0,0,0,0,0,0,0};
    if (r < NTF_) {
      const float4* p = (const float4*)(hV + (size_t)(n0 + r) * H_ + u * 8);
      float4 f0 = p[0], f1 = p[1];
      float xv[8] = {f0.x, f0.y, f0.z, f0.w, f1.x, f1.y, f1.z, f1.w};
      #pragma unroll
      for (int e = 0; e < 8; e++) {
        ushort_t hb = bf16rn(xv[e]);
        h8[e] = (short)hb;
        l8[e] = (short)bf16rn(xv[e] - bf16tof(hb));
      }
    }
    int us = u ^ (r & 15);
    *(short8*)&xhi[r * 128 + us * 8] = h8;
    *(short8*)&xlo[r * 128 + us * 8] = l8;
  }
  __syncthreads();

  short8 axh[4], axl[4];
  #pragma unroll
  for (int ks = 0; ks < 4; ks++) {
    int us = ((ks * 4 + g) ^ c0) * 8;
    axh[ks] = *(const short8*)&xhi[c0 * 128 + us];
    axl[ks] = *(const short8*)&xlo[c0 * 128 + us];
  }

  ushort_t* myhhi = &hpl[w][0];
  ushort_t* myhlo = &hpl[w][16 * H_];
  f32x4 accO[8];
  #pragma unroll
  for (int nt = 0; nt < 8; nt++) accO[nt] = f32x4{0.f, 0.f, 0.f, 0.f};

  #pragma unroll
  for (int cc = 0; cc < 2; cc++) {
    int c = 2 * w + cc;
    f32x4 a1[8];
    #pragma unroll
    for (int nt = 0; nt < 8; nt++) a1[nt] = f32x4{0.f, 0.f, 0.f, 0.f};
    #pragma unroll
    for (int ks = 0; ks < 4; ks++) {
      #pragma unroll
      for (int nt = 0; nt < 8; nt++) {
        size_t boff = (size_t)(((ks * 32 + (c * 8 + nt)) * 64 + l) * 8);
        short8 bh = *(const short8*)(w1hi + boff);
        short8 bl = *(const short8*)(w1lo + boff);
        a1[nt] = __builtin_amdgcn_mfma_f32_16x16x32_bf16(axh[ks], bh, a1[nt], 0, 0, 0);
        a1[nt] = __builtin_amdgcn_mfma_f32_16x16x32_bf16(axl[ks], bh, a1[nt], 0, 0, 0);
        a1[nt] = __builtin_amdgcn_mfma_f32_16x16x32_bf16(axh[ks], bl, a1[nt], 0, 0, 0);
        a1[nt] = __builtin_amdgcn_mfma_f32_16x16x32_bf16(axl[ks], bl, a1[nt], 0, 0, 0);
      }
    }
    #pragma unroll
    for (int nt = 0; nt < 8; nt++) {
      int col = nt * 16 + c0;
      float bb = b1[c * 128 + col];
      #pragma unroll
      for (int j = 0; j < 4; j++) {
        int row = g * 4 + j;
        float hv = fmaxf(a1[nt][j] + bb, 0.f);
        ushort_t hb = bf16rn(hv);
        ushort_t lb = bf16rn(hv - bf16tof(hb));
        int us2 = ((col >> 3) ^ row) * 8 + (col & 7);
        myhhi[row * 128 + us2] = hb;
        myhlo[row * 128 + us2] = lb;
      }
    }
    #pragma unroll
    for (int ks = 0; ks < 4; ks++) {
      int us2 = ((ks * 4 + g) ^ c0) * 8;
      short8 ahh = *(const short8*)&myhhi[c0 * 128 + us2];
      short8 ahl = *(const short8*)&myhlo[c0 * 128 + us2];
      #pragma unroll
      for (int nt = 0; nt < 8; nt++) {
        size_t boff = (size_t)((((c * 4 + ks) * 8 + nt) * 64 + l) * 8);
        short8 bh = *(const short8*)(w2hi + boff);
        short8 bl = *(const short8*)(w2lo + boff);
        accO[nt] = __builtin_amdgcn_mfma_f32_16x16x32_bf16(ahh, bh, accO[nt], 0, 0, 0);
        accO[nt] = __builtin_amdgcn_mfma_f32_16x16x32_bf16(ahl, bh, accO[nt], 0, 0, 0);
        accO[nt] = __builtin_amdgcn_mfma_f32_16x16x32_bf16(ahh, bl, accO[nt], 0, 0, 0);
        accO[nt] = __builtin_amdgcn_mfma_f32_16x16x32_bf16(ahl, bl, accO[nt], 0, 0, 0);
      }
    }
  }

  if (w == 0) {
    #pragma unroll
    for (int nt = 0; nt < 8; nt++) {
      #pragma unroll
      for (int j = 0; j < 4; j++) {
        int row = g * 4 + j;
        if (row < NTF_) obuf[row * H_ + nt * 16 + c0] = accO[nt][j];
      }
    }
  }
  __syncthreads();
  if (w == 1) {
    #pragma unroll
    for (int nt = 0; nt < 8; nt++) {
      #pragma unroll
      for (int j = 0; j < 4; j++) {
        int row = g * 4 + j;
        if (row < NTF_) obuf[row * H_ + nt * 16 + c0] += accO[nt][j];
      }
    }
  }
  __syncthreads();

  float rv[NTF_];
  {
    int un = t >> 3, e = t & 7;
    float bb = b2[t];
    #pragma unroll
    for (int u = 0; u < NTF_; u++) {
      int us = (un ^ u) * 8 + e;
      float xr = bf16tof(xhi[u * 128 + us]) + bf16tof(xlo[u * 128 + us]);
      rv[u] = xr + obuf[u * H_ + t] + bb;
    }
  }
  #pragma unroll
  for (int u = 0; u < NTF_; u++) obuf[u * H_ + t] = rv[u];
  __syncthreads();
  {
    int row = t >> 3, li = t & 7;
    float s = 0.f;
    if (row < NTF_) {
      for (int i = 0; i < 16; i++) s += obuf[row * H_ + li + 8 * i];
    }
    s += __shfl_xor(s, 1, 64); s += __shfl_xor(s, 2, 64); s += __shfl_xor(s, 4, 64);
    float mean = s * (1.f / H_);
    float vs = 0.f;
    if (row < NTF_) {
      for (int i = 0; i < 16; i++) {
        float d = obuf[row * H_ + li + 8 * i] - mean;
        vs = fmaf(d, d, vs);
      }
    }
    vs += __shfl_xor(vs, 1, 64); vs += __shfl_xor(vs, 2, 64); vs += __shfl_xor(vs, 4, 64);
    if (li == 0 && row < NTF_) { mst[row] = mean; ist[row] = rsqrtf(vs * (1.f / H_) + 1e-6f); }
  }
  __syncthreads();
  #pragma unroll
  for (int u = 0; u < NTF_; u++) {
    float y = (rv[u] - mst[u]) * ist[u] * mask[n0 + u];
    hV[(size_t)(n0 + u) * H_ + t] = y;
  }
}

// ---------------- output: log_softmax(hV @ W_out + b_out), fp32, 2 nodes/block ----------------
__global__ __launch_bounds__(128) void out_kernel(const float* __restrict__ hV,
    const float* __restrict__ Wout, const float* __restrict__ bout, float* __restrict__ out) {
  int g = threadIdx.x >> 6, t = threadIdx.x & 63;
  int node = blockIdx.x * 2 + g;
  __shared__ float x[2][H_];
  __shared__ float lg[2][V_];
  __shared__ float lse[2];
  x[g][t] = hV[(size_t)node * H_ + t];
  x[g][t + 64] = hV[(size_t)node * H_ + t + 64];
  __syncthreads();
  if (t < V_) {
    float a = bout[t];
    for (int h = 0; h < H_; h++) a = fmaf(x[g][h], Wout[h * V_ + t], a);
    lg[g][t] = a;
  }
  __syncthreads();
  if (t == 0) {
    float mx = -3.4e38f;
    for (int v = 0; v < V_; v++) mx = fmaxf(mx, lg[g][v]);
    float s = 0.f;
    for (int v = 0; v < V_; v++) s += expf(lg[g][v] - mx);
    lse[g] = mx + logf(s);
  }
  __syncthreads();
  if (t < V_) out[(size_t)node * V_ + t] = lg[g][t] - lse[g];
}

// ---------------- host ----------------
extern "C" void kernel_launch(void* const* d_in, const int* in_sizes, int n_in,
                              void* d_out, int out_size, void* d_ws, size_t ws_size,
                              hipStream_t stream) {
  const float* X    = (const float*)d_in[0];
  const float* mask = (const float*)d_in[1];
  const int*   S    = (const int*)d_in[2];
  const float* Wfn  = (const float*)d_in[3];
  const float* bfn  = (const float*)d_in[4];
  const float* Wfe  = (const float*)d_in[5];
  const float* bfe  = (const float*)d_in[6];
  const float* Wv   = (const float*)d_in[7];
  const float* bv   = (const float*)d_in[8];
  const float* We   = (const float*)d_in[9];
  const float* be   = (const float*)d_in[10];
  const float* Ws   = (const float*)d_in[11];
  const float* eWQ  = (const float*)d_in[12];
  const float* eWK  = (const float*)d_in[13];
  const float* eWV  = (const float*)d_in[14];
  const float* eWO  = (const float*)d_in[15];
  const float* eW1  = (const float*)d_in[16];
  const float* eb1  = (const float*)d_in[17];
  const float* eW2  = (const float*)d_in[18];
  const float* eb2  = (const float*)d_in[19];
  const float* dWQ  = (const float*)d_in[20];
  const float* dWK  = (const float*)d_in[21];
  const float* dWV  = (const float*)d_in[22];
  const float* dWO  = (const float*)d_in[23];
  const float* dW1  = (const float*)d_in[24];
  const float* db1  = (const float*)d_in[25];
  const float* dW2  = (const float*)d_in[26];
  const float* db2  = (const float*)d_in[27];
  const float* Wout = (const float*)d_in[28];
  const float* bout = (const float*)d_in[29];
  float* out = (float*)d_out;

  char* w = (char*)d_ws;
  int*    eidx = (int*)w;     w += (size_t)BN_ * K_ * 4;
  float*  dnb  = (float*)w;   w += (size_t)BN_ * K_ * 4;
  float*  vf   = (float*)w;   w += (size_t)BN_ * 6 * 4;
  float*  hVa  = (float*)w;   w += (size_t)BN_ * H_ * 4;
  float*  hVb  = (float*)w;   w += (size_t)BN_ * H_ * 4;
  float*  hVc  = (float*)w;   w += (size_t)BN_ * H_ * 4;
  float*  nKb  = (float*)w;   w += (size_t)BN_ * H_ * 4;
  float*  nVb  = (float*)w;   w += (size_t)BN_ * H_ * 4;
  float*  nKe  = (float*)w;   w += (size_t)BN_ * H_ * 4;
  float*  nVe  = (float*)w;   w += (size_t)BN_ * H_ * 4;
  float*  hE   = (float*)w;   w += (size_t)BN_ * K_ * H_ * 4;
  float*  wkt  = (float*)w;   w += (size_t)6 * FRAG_ * 4;       // WK1^T, 6 layers
  ushort_t* wf2Hi = (ushort_t*)w; w += (size_t)12 * FRAG2_ * 2;
  ushort_t* wf2Lo = (ushort_t*)w; w += (size_t)12 * FRAG2_ * 2;
  ushort_t* feHi = (ushort_t*)w; w += (size_t)4096 * 2;
  ushort_t* feLo = (ushort_t*)w; w += (size_t)4096 * 2;
  ushort_t* weHi = (ushort_t*)w; w += (size_t)FRAG_ * 2;
  ushort_t* weLo = (ushort_t*)w; w += (size_t)FRAG_ * 2;

  topk_kernel<<<BN_ / TQ_, 256, 0, stream>>>(X, mask, eidx, dnb);
  dihedral_kernel<<<(BN_ + 255) / 256, 256, 0, stream>>>(X, vf);
  node_embed_kernel<<<BN_, H_, 0, stream>>>(vf, Wfn, bfn, Wv, bv, hVa);
  prep_edge_w_kernel<<<2, 256, 0, stream>>>(Wfe, We, feHi, feLo, weHi, weLo);
  edge_embed_kernel<<<BN_ * K_ / EEB_, 128, 0, stream>>>(eidx, dnb, feHi, feLo, bfe, weHi, weLo, be, hE);
  prep_wkt_kernel<<<6, 256, 0, stream>>>(eWK, dWK, wkt);
  prep_wfrag2_kernel<<<12, 256, 0, stream>>>(eW1, eW2, dW1, dW2, wf2Hi, wf2Lo);

  // encoder: a->b, b->a, a->b
  float* cur = hVa; float* nxt = hVb;
  for (int l = 0; l < 3; l++) {
    const float* WK = eWK + (size_t)l * 2 * H_ * H_;
    const float* WV = eWV + (size_t)l * 2 * H_ * H_;
    node_proj_kernel<<<BN_ / 16, H_, 0, stream>>>(cur,
        WK + (size_t)H_ * H_, WV + (size_t)H_ * H_, nKb, nVb);
    attn_kernel<true><<<BN_ / ANT_, 128, 0, stream>>>(cur, hE, eidx, mask,
        eWQ + (size_t)l * H_ * H_,
        wkt + (size_t)l * FRAG_,
        WV,                               // WV1: first HxH block, original layout
        eWO + (size_t)l * H_ * H_,
        nKb, nVb, nullptr, nullptr, nxt);
    ffn_kernel<<<BN_ / NTF_, 128, 0, stream>>>(nxt, mask,
        wf2Hi + (size_t)l * FRAG2_, wf2Lo + (size_t)l * FRAG2_,
        wf2Hi + (size_t)(3 + l) * FRAG2_, wf2Lo + (size_t)(3 + l) * FRAG2_,
        eb1 + (size_t)l * 4 * H_, eb2 + (size_t)l * H_);
    float* tmp = cur; cur = nxt; nxt = tmp;
  }
  float* henc = cur;  // = hVb
  // decoder: henc->a, a->c, c->a (henc preserved)
  float* din = henc;
  float* douts[3] = { hVa, hVc, hVa };
  for (int l = 0; l < 3; l++) {
    const float* WK = dWK + (size_t)l * 3 * H_ * H_;
    const float* WV = dWV + (size_t)l * 3 * H_ * H_;
    node_proj3_kernel<<<BN_ / 8, H_, 0, stream>>>(S, Ws, din, henc,
        WK + (size_t)H_ * H_, WV + (size_t)H_ * H_,
        WK + (size_t)2 * H_ * H_, WV + (size_t)2 * H_ * H_,
        nKb, nVb, nKe, nVe);
    attn_kernel<false><<<BN_ / ANT_, 128, 0, stream>>>(din, hE, eidx, mask,
        dWQ + (size_t)l * H_ * H_,
        wkt + (size_t)(3 + l) * FRAG_,
        WV,                               // WV1: first HxH block, original layout
        dWO + (size_t)l * H_ * H_,
        nKb, nVb, nKe, nVe, douts[l]);
    ffn_kernel<<<BN_ / NTF_, 128, 0, stream>>>(douts[l], mask,
        wf2Hi + (size_t)(6 + l) * FRAG2_, wf2Lo + (size_t)(6 + l) * FRAG2_,
        wf2Hi + (size_t)(9 + l) * FRAG2_, wf2Lo + (size_t)(9 + l) * FRAG2_,
        db1 + (size_t)l * 4 * H_, db2 + (size_t)l * H_);
    din = douts[l];
  }
  out_kernel<<<BN_ / 2, 128, 0, stream>>>(din, Wout, bout, out);
}

// Round 14
// 1603.694 us; speedup vs baseline: 1.2594x; 1.2594x over previous
//
#include <hip/hip_runtime.h>
#include <hip/hip_bf16.h>
#include <math.h>

#define DEVFN __device__ __forceinline__

constexpr int B_ = 16, N_ = 512, K_ = 30, H_ = 128;
constexpr int NH_ = 4, V_ = 20;
constexpr int BN_ = B_ * N_;
constexpr float NEG_INF_ = -3.4028235e38f;
constexpr int FRAG_ = H_ * H_;        // 16384 elems per 128x128 plane
constexpr int FRAG2_ = H_ * 4 * H_;   // 65536 elems per 128x512 / 512x128 plane

typedef unsigned short ushort_t;
using short8 = __attribute__((ext_vector_type(8))) short;
using f32x4  = __attribute__((ext_vector_type(4))) float;

DEVFN ushort_t bf16rn(float x) {
  unsigned u = __float_as_uint(x);
  return (ushort_t)((u + 0x7fffu + ((u >> 16) & 1u)) >> 16);
}
DEVFN float bf16tof(ushort_t h) { return __uint_as_float(((unsigned)h) << 16); }

// ---------------- top-K neighbors: distances BIT-EXACT to plain numpy float32 ----------------
// DO NOT TOUCH the distance math / tie-break. R6 rewrite: register-resident selection,
// 4 queries/block (1 wave each); zero barriers/LDS in the K-loop. Bit-identical output.
constexpr int TQ_ = 4;
__global__ __launch_bounds__(256) void topk_kernel(const float* __restrict__ X,
    const float* __restrict__ mask, int* __restrict__ E_idx, float* __restrict__ Dnb) {
  __shared__ float xs[N_ * 3];
  __shared__ float ms[N_];
  int blk = blockIdx.x;
  int b = blk / (N_ / TQ_);
  int i0 = (blk % (N_ / TQ_)) * TQ_;
  int t = threadIdx.x;
  int wv = t >> 6, l = t & 63;
  for (int j = t; j < N_; j += 256) {
    const float* p = X + ((size_t)(b * N_ + j) * 4 + 1) * 3;  // CA atom
    xs[j * 3 + 0] = p[0]; xs[j * 3 + 1] = p[1]; xs[j * 3 + 2] = p[2];
    ms[j] = mask[b * N_ + j];
  }
  __syncthreads();
  const int i = i0 + wv;
  const float xi0 = xs[i * 3], xi1 = xs[i * 3 + 1], xi2 = xs[i * 3 + 2];
  const float mi = ms[i];
  float D[8];
  float lmax = -3.4e38f;
  #pragma unroll
  for (int e = 0; e < 8; e++) {
    int j = l * 8 + e;
    float dx = __fsub_rn(xi0, xs[j * 3]);
    float dy = __fsub_rn(xi1, xs[j * 3 + 1]);
    float dz = __fsub_rn(xi2, xs[j * 3 + 2]);
    float m2 = __fmul_rn(mi, ms[j]);
    float s = __fadd_rn(__fadd_rn(__fadd_rn(__fmul_rn(dx, dx), __fmul_rn(dy, dy)),
                                  __fmul_rn(dz, dz)), 1e-6f);
    float Dv = __fmul_rn(m2, __fsqrt_rn(s));
    D[e] = Dv;
    lmax = fmaxf(lmax, Dv);
  }
  #pragma unroll
  for (int off = 32; off > 0; off >>= 1) lmax = fmaxf(lmax, __shfl_xor(lmax, off, 64));
  unsigned long long key[8];
  unsigned long long lmin = ~0ull;
  #pragma unroll
  for (int e = 0; e < 8; e++) {
    int j = l * 8 + e;
    float m2 = __fmul_rn(mi, ms[j]);
    float d = __fadd_rn(D[e], __fmul_rn(__fsub_rn(1.f, m2), lmax));
    unsigned long long k = (((unsigned long long)__float_as_uint(d)) << 32)
                         | (unsigned)(N_ - 1 - j);
    key[e] = k;
    if (k < lmin) lmin = k;
  }
  for (int kk = 0; kk < K_; kk++) {
    unsigned long long m = lmin;
    #pragma unroll
    for (int off = 32; off > 0; off >>= 1) {
      unsigned long long o = __shfl_xor(m, off, 64);
      if (o < m) m = o;
    }
    int j = N_ - 1 - (int)(m & 0xffffffffull);
    if (l == 0) {
      E_idx[(size_t)(b * N_ + i) * K_ + kk] = j;
      Dnb[(size_t)(b * N_ + i) * K_ + kk] = __uint_as_float((unsigned)(m >> 32));
    }
    if ((j >> 3) == l) {
      key[j & 7] = ~0ull;
      unsigned long long nm = key[0];
      #pragma unroll
      for (int e = 1; e < 8; e++) if (key[e] < nm) nm = key[e];
      lmin = nm;
    }
  }
}

// ---------------- dihedral features (1 thread / node), fp32 ----------------
DEVFN void load_atom(const float* X, int b, int m, float* p) {
  const float* q = X + ((size_t)(b * N_ + m / 3) * 4 + (m % 3)) * 3;
  p[0] = q[0]; p[1] = q[1]; p[2] = q[2];
}
DEVFN void cross3(const float* a, const float* b, float* c) {
  c[0] = a[1] * b[2] - a[2] * b[1];
  c[1] = a[2] * b[0] - a[0] * b[2];
  c[2] = a[0] * b[1] - a[1] * b[0];
}
DEVFN void norm3(float* v) {
  float n = sqrtf(v[0] * v[0] + v[1] * v[1] + v[2] * v[2]) + 1e-7f;
  v[0] /= n; v[1] /= n; v[2] /= n;
}
__global__ __launch_bounds__(256) void dihedral_kernel(const float* __restrict__ X, float* __restrict__ Vf) {
  int idx = blockIdx.x * blockDim.x + threadIdx.x;
  if (idx >= BN_) return;
  int b = idx / N_, n = idx % N_;
  float cs[3], sn[3];
  for (int s = 0; s < 3; s++) {
    int p = 3 * n + s;
    float a = 0.f;
    if (p >= 1 && p <= 3 * N_ - 3) {
      int tt = p - 1;
      float u[3][3], prev[3], cur[3];
      load_atom(X, b, tt, prev);
      for (int q = 0; q < 3; q++) {
        load_atom(X, b, tt + q + 1, cur);
        float d0 = cur[0] - prev[0], d1 = cur[1] - prev[1], d2 = cur[2] - prev[2];
        float nr = sqrtf(d0 * d0 + d1 * d1 + d2 * d2) + 1e-7f;
        u[q][0] = d0 / nr; u[q][1] = d1 / nr; u[q][2] = d2 / nr;
        prev[0] = cur[0]; prev[1] = cur[1]; prev[2] = cur[2];
      }
      float n2v[3], n1v[3];
      cross3(u[0], u[1], n2v); norm3(n2v);
      cross3(u[1], u[2], n1v); norm3(n1v);
      float cd = n2v[0] * n1v[0] + n2v[1] * n1v[1] + n2v[2] * n1v[2];
      cd = fminf(fmaxf(cd, -1.f + 1e-7f), 1.f - 1e-7f);
      float dt = u[0][0] * n1v[0] + u[0][1] * n1v[1] + u[0][2] * n1v[2];
      float sg = (dt > 0.f) ? 1.f : ((dt < 0.f) ? -1.f : 0.f);
      a = sg * acosf(cd);
    }
    cs[s] = cosf(a); sn[s] = sinf(a);
  }
  float* o = Vf + (size_t)idx * 6;
  o[0] = cs[0]; o[1] = cs[1]; o[2] = cs[2]; o[3] = sn[0]; o[4] = sn[1]; o[5] = sn[2];
}

// ---------------- node embed: hV = LN(V@Wfn+bfn) @ Wv + bv (fp32, shuffle-LN) ----------------
__global__ __launch_bounds__(H_) void node_embed_kernel(const float* __restrict__ Vf,
    const float* __restrict__ Wfn, const float* __restrict__ bfn,
    const float* __restrict__ Wv, const float* __restrict__ bv, float* __restrict__ hV) {
  int node = blockIdx.x, t = threadIdx.x;
  const int w = t >> 6, l = t & 63;
  __shared__ float v6[6];
  __shared__ __attribute__((aligned(16))) float t1[H_];
  __shared__ float wred[2];
  if (t < 6) v6[t] = Vf[(size_t)node * 6 + t];
  __syncthreads();
  float acc = bfn[t];
  for (int f = 0; f < 6; f++) acc = fmaf(v6[f], Wfn[f * H_ + t], acc);
  float s1 = acc;
  #pragma unroll
  for (int off = 32; off > 0; off >>= 1) s1 += __shfl_xor(s1, off, 64);
  if (l == 0) wred[w] = s1;
  __syncthreads();
  float mean = (wred[0] + wred[1]) * (1.f / H_);
  float d0 = acc - mean;
  float s2 = d0 * d0;
  #pragma unroll
  for (int off = 32; off > 0; off >>= 1) s2 += __shfl_xor(s2, off, 64);
  __syncthreads();
  if (l == 0) wred[w] = s2;
  __syncthreads();
  float var = (wred[0] + wred[1]) * (1.f / H_);
  t1[t] = d0 * rsqrtf(var + 1e-6f);
  __syncthreads();
  float o = bv[t];
  for (int j4 = 0; j4 < H_ / 4; j4++) {
    float4 xv = ((const float4*)t1)[j4];
    int j = j4 * 4;
    o = fmaf(xv.x, Wv[(j + 0) * H_ + t],
        fmaf(xv.y, Wv[(j + 1) * H_ + t],
        fmaf(xv.z, Wv[(j + 2) * H_ + t],
        fmaf(xv.w, Wv[(j + 3) * H_ + t], o))));
  }
  hV[(size_t)node * H_ + t] = o;
}

// ---------------- prep Wfe (32x128) + We (128x128) -> MFMA B-frag bf16 hi/lo ----------------
__global__ __launch_bounds__(256) void prep_edge_w_kernel(const float* __restrict__ Wfe,
    const float* __restrict__ We, ushort_t* __restrict__ feHi, ushort_t* __restrict__ feLo,
    ushort_t* __restrict__ weHi, ushort_t* __restrict__ weLo) {
  if (blockIdx.x == 0) {
    for (int i = 0; i < 4096 / 256; i++) {
      int lin = i * 256 + threadIdx.x;   // k*128 + c, k<32
      int k = lin >> 7, c = lin & 127;
      float x = Wfe[lin];
      int gk = k >> 3, j = k & 7;
      int nt = c >> 4, cc = c & 15;
      int oidx = (nt * 64 + gk * 16 + cc) * 8 + j;
      ushort_t hb = bf16rn(x);
      feHi[oidx] = hb;
      feLo[oidx] = bf16rn(x - bf16tof(hb));
    }
  } else {
    for (int i = 0; i < FRAG_ / 256; i++) {
      int lin = i * 256 + threadIdx.x;
      int k = lin >> 7, c = lin & 127;
      float x = We[lin];
      int ks = k >> 5, gk = (k >> 3) & 3, j = k & 7;
      int nt = c >> 4, cc = c & 15;
      int oidx = ((ks * 8 + nt) * 64 + gk * 16 + cc) * 8 + j;
      ushort_t hb = bf16rn(x);
      weHi[oidx] = hb;
      weLo[oidx] = bf16rn(x - bf16tof(hb));
    }
  }
}

// ---------------- prep WK1T: transpose first HxH block of attn K-weights (fp32) ----------------
__global__ __launch_bounds__(256) void prep_wkt_kernel(const float* __restrict__ eWK,
    const float* __restrict__ dWK, float* __restrict__ outT) {
  int m = blockIdx.x;  // 0..2 enc, 3..5 dec
  const float* W = (m < 3) ? (eWK + (size_t)m * 2 * H_ * H_)
                           : (dWK + (size_t)(m - 3) * 3 * H_ * H_);
  float* o = outT + (size_t)m * FRAG_;
  for (int i = 0; i < FRAG_ / 256; i++) {
    int lin = i * 256 + threadIdx.x;   // lin = c*H + f (coalesced write)
    int c = lin >> 7, f = lin & 127;
    o[lin] = W[f * H_ + c];
  }
}

// ---------------- edge embed via split-bf16 MFMA: hE = LN(E@Wfe+bfe) @ We + be ----------------
constexpr int EEB_ = 32;
constexpr int FPS_ = 40;   // feats plane stride in shorts
__global__ __launch_bounds__(128) void edge_embed_kernel(const int* __restrict__ E_idx,
    const float* __restrict__ Dnb,
    const ushort_t* __restrict__ feHi, const ushort_t* __restrict__ feLo,
    const float* __restrict__ bfe,
    const ushort_t* __restrict__ weHi, const ushort_t* __restrict__ weLo,
    const float* __restrict__ be, float* __restrict__ hE) {
  int e0 = blockIdx.x * EEB_, t = threadIdx.x;
  const int w = t >> 6, l = t & 63, c0 = l & 15, g = l >> 4;
  __shared__ ushort_t fhi[EEB_ * FPS_], flo[EEB_ * FPS_];
  __shared__ __attribute__((aligned(16))) char sbuf[EEB_ * H_ * 4];
  float* buf = (float*)sbuf;
  ushort_t* p2hi = (ushort_t*)sbuf;
  ushort_t* p2lo = (ushort_t*)(sbuf + EEB_ * H_ * 2);
  __shared__ float mst[EEB_], ist[EEB_];

  #pragma unroll
  for (int it = 0; it < 8; it++) {
    int id = it * 128 + t;
    int r = id >> 5, f = id & 31;
    int e = e0 + r;
    int n = (e / K_) % N_;
    float v;
    if (f < 16) {
      int jj = (f < 8) ? f : (f - 8);
      float freq = expf(-logf(10000.f) * (2.f * jj) / 16.f);
      float ang = (float)(E_idx[e] - n) * freq;
      v = (f < 8) ? cosf(ang) : sinf(ang);
    } else {
      int rr = f - 16;
      float mu = 20.f * (float)rr / 15.f;
      float z = (Dnb[e] - mu) * (1.f / 1.25f);
      v = expf(-z * z);
    }
    ushort_t hb = bf16rn(v);
    fhi[r * FPS_ + f] = hb;
    flo[r * FPS_ + f] = bf16rn(v - bf16tof(hb));
  }
  __syncthreads();

  {
    short8 ah[2], al[2];
    #pragma unroll
    for (int mt = 0; mt < 2; mt++) {
      int r = mt * 16 + c0;
      ah[mt] = *(const short8*)&fhi[r * FPS_ + g * 8];
      al[mt] = *(const short8*)&flo[r * FPS_ + g * 8];
    }
    #pragma unroll
    for (int nt = 0; nt < 4; nt++) {
      int ntg = w * 4 + nt;
      size_t boff = (size_t)((ntg * 64 + l) * 8);
      short8 bh = *(const short8*)(feHi + boff);
      short8 bl = *(const short8*)(feLo + boff);
      int c = ntg * 16 + c0;
      float bb = bfe[c];
      #pragma unroll
      for (int mt = 0; mt < 2; mt++) {
        f32x4 a = f32x4{0.f, 0.f, 0.f, 0.f};
        a = __builtin_amdgcn_mfma_f32_16x16x32_bf16(ah[mt], bh, a, 0, 0, 0);
        a = __builtin_amdgcn_mfma_f32_16x16x32_bf16(al[mt], bh, a, 0, 0, 0);
        a = __builtin_amdgcn_mfma_f32_16x16x32_bf16(ah[mt], bl, a, 0, 0, 0);
        a = __builtin_amdgcn_mfma_f32_16x16x32_bf16(al[mt], bl, a, 0, 0, 0);
        #pragma unroll
        for (int j = 0; j < 4; j++) {
          int row = mt * 16 + g * 4 + j;
          buf[row * H_ + c] = a[j] + bb;
        }
      }
    }
  }
  __syncthreads();

  {
    int row = t >> 2, li = t & 3;
    float s = 0.f;
    for (int i = 0; i < 32; i++) {
      int col = li + 4 * ((i + row) & 31);
      s += buf[row * H_ + col];
    }
    s += __shfl_xor(s, 1, 64); s += __shfl_xor(s, 2, 64);
    float mean = s * (1.f / H_);
    float vs = 0.f;
    for (int i = 0; i < 32; i++) {
      int col = li + 4 * ((i + row) & 31);
      float d = buf[row * H_ + col] - mean;
      vs = fmaf(d, d, vs);
    }
    vs += __shfl_xor(vs, 1, 64); vs += __shfl_xor(vs, 2, 64);
    if (li == 0) { mst[row] = mean; ist[row] = rsqrtf(vs * (1.f / H_) + 1e-6f); }
  }
  __syncthreads();

  float vreg[32];
  #pragma unroll
  for (int it = 0; it < 4; it++) {
    int id = it * 128 + t;
    int r = id >> 4, u = id & 15;
    float mean = mst[r], inv = ist[r];
    #pragma unroll
    for (int e2 = 0; e2 < 8; e2++) vreg[it * 8 + e2] = (buf[r * H_ + u * 8 + e2] - mean) * inv;
  }
  __syncthreads();
  #pragma unroll
  for (int it = 0; it < 4; it++) {
    int id = it * 128 + t;
    int r = id >> 4, u = id & 15;
    short8 h8, l8;
    #pragma unroll
    for (int e2 = 0; e2 < 8; e2++) {
      float x = vreg[it * 8 + e2];
      ushort_t hb = bf16rn(x);
      h8[e2] = (short)hb;
      l8[e2] = (short)bf16rn(x - bf16tof(hb));
    }
    int us = u ^ (r & 15);
    *(short8*)&p2hi[r * 128 + us * 8] = h8;
    *(short8*)&p2lo[r * 128 + us * 8] = l8;
  }
  __syncthreads();

  short8 ah2[2][4], al2[2][4];
  #pragma unroll
  for (int mt = 0; mt < 2; mt++) {
    int r = mt * 16 + c0;
    #pragma unroll
    for (int ks = 0; ks < 4; ks++) {
      int us = (ks * 4 + g) ^ c0;
      ah2[mt][ks] = *(const short8*)&p2hi[r * 128 + us * 8];
      al2[mt][ks] = *(const short8*)&p2lo[r * 128 + us * 8];
    }
  }
  f32x4 acc2[2][4];
  #pragma unroll
  for (int mt = 0; mt < 2; mt++)
    #pragma unroll
    for (int nt = 0; nt < 4; nt++) acc2[mt][nt] = f32x4{0.f, 0.f, 0.f, 0.f};
  #pragma unroll
  for (int ks = 0; ks < 4; ks++) {
    #pragma unroll
    for (int nt = 0; nt < 4; nt++) {
      int ntg = w * 4 + nt;
      size_t boff = (size_t)(((ks * 8 + ntg) * 64 + l) * 8);
      short8 bh = *(const short8*)(weHi + boff);
      short8 bl = *(const short8*)(weLo + boff);
      #pragma unroll
      for (int mt = 0; mt < 2; mt++) {
        acc2[mt][nt] = __builtin_amdgcn_mfma_f32_16x16x32_bf16(ah2[mt][ks], bh, acc2[mt][nt], 0, 0, 0);
        acc2[mt][nt] = __builtin_amdgcn_mfma_f32_16x16x32_bf16(al2[mt][ks], bh, acc2[mt][nt], 0, 0, 0);
        acc2[mt][nt] = __builtin_amdgcn_mfma_f32_16x16x32_bf16(ah2[mt][ks], bl, acc2[mt][nt], 0, 0, 0);
        acc2[mt][nt] = __builtin_amdgcn_mfma_f32_16x16x32_bf16(al2[mt][ks], bl, acc2[mt][nt], 0, 0, 0);
      }
    }
  }
  #pragma unroll
  for (int mt = 0; mt < 2; mt++) {
    #pragma unroll
    for (int nt = 0; nt < 4; nt++) {
      int c = (w * 4 + nt) * 16 + c0;
      float bb = be[c];
      #pragma unroll
      for (int j = 0; j < 4; j++) {
        int row = mt * 16 + g * 4 + j;
        hE[(size_t)(e0 + row) * H_ + c] = acc2[mt][nt][j] + bb;
      }
    }
  }
}

// ---------------- per-node projection (encoder): oa/ob = x@Wa/Wb ----------------
__global__ __launch_bounds__(128) void node_proj_kernel(const float* __restrict__ x1,
    const float* __restrict__ Wa1, const float* __restrict__ Wb1,
    float* __restrict__ oa, float* __restrict__ ob) {
  constexpr int NT = 16;
  int n0 = blockIdx.x * NT, t = threadIdx.x;
  __shared__ __attribute__((aligned(16))) float xs1[NT * H_];
  #pragma unroll
  for (int u = 0; u < NT; u++) xs1[u * H_ + t] = x1[(size_t)(n0 + u) * H_ + t];
  __syncthreads();
  float aa[NT], ab[NT];
  #pragma unroll
  for (int u = 0; u < NT; u++) { aa[u] = 0.f; ab[u] = 0.f; }
  for (int j4 = 0; j4 < H_ / 4; j4++) {
    int j = j4 * 4;
    float wa0 = Wa1[(j + 0) * H_ + t], wa1 = Wa1[(j + 1) * H_ + t];
    float wa2 = Wa1[(j + 2) * H_ + t], wa3 = Wa1[(j + 3) * H_ + t];
    float wb0 = Wb1[(j + 0) * H_ + t], wb1 = Wb1[(j + 1) * H_ + t];
    float wb2 = Wb1[(j + 2) * H_ + t], wb3 = Wb1[(j + 3) * H_ + t];
    #pragma unroll
    for (int u = 0; u < NT; u++) {
      float4 xv = ((const float4*)(xs1 + u * H_))[j4];
      aa[u] = fmaf(xv.x, wa0, fmaf(xv.y, wa1, fmaf(xv.z, wa2, fmaf(xv.w, wa3, aa[u]))));
      ab[u] = fmaf(xv.x, wb0, fmaf(xv.y, wb1, fmaf(xv.z, wb2, fmaf(xv.w, wb3, ab[u]))));
    }
  }
  #pragma unroll
  for (int u = 0; u < NT; u++) {
    oa[(size_t)(n0 + u) * H_ + t] = aa[u];
    ob[(size_t)(n0 + u) * H_ + t] = ab[u];
  }
}

// ---------------- decoder fused projection ----------------
__global__ __launch_bounds__(128) void node_proj3_kernel(const int* __restrict__ S,
    const float* __restrict__ Ws, const float* __restrict__ din, const float* __restrict__ henc,
    const float* __restrict__ WK2, const float* __restrict__ WV2,
    const float* __restrict__ WK3, const float* __restrict__ WV3,
    float* __restrict__ nKb, float* __restrict__ nVb,
    float* __restrict__ nKe, float* __restrict__ nVe) {
  constexpr int NT = 8;
  int n0 = blockIdx.x * NT, t = threadIdx.x;
  __shared__ __attribute__((aligned(16))) float xs1[NT * H_];  // hS
  __shared__ __attribute__((aligned(16))) float xs2[NT * H_];  // din
  __shared__ __attribute__((aligned(16))) float xs3[NT * H_];  // henc
  #pragma unroll
  for (int u = 0; u < NT; u++) {
    int node = n0 + u;
    xs1[u * H_ + t] = Ws[(size_t)S[node] * H_ + t];
    xs2[u * H_ + t] = din[(size_t)node * H_ + t];
    xs3[u * H_ + t] = henc[(size_t)node * H_ + t];
  }
  __syncthreads();
  float aKb[NT], aVb[NT], aKe[NT], aVe[NT];
  #pragma unroll
  for (int u = 0; u < NT; u++) { aKb[u] = 0.f; aVb[u] = 0.f; aKe[u] = 0.f; aVe[u] = 0.f; }
  for (int j4 = 0; j4 < H_ / 4; j4++) {
    int j = j4 * 4;
    float k20 = WK2[(j + 0) * H_ + t], k21 = WK2[(j + 1) * H_ + t];
    float k22 = WK2[(j + 2) * H_ + t], k23 = WK2[(j + 3) * H_ + t];
    float v20 = WV2[(j + 0) * H_ + t], v21 = WV2[(j + 1) * H_ + t];
    float v22 = WV2[(j + 2) * H_ + t], v23 = WV2[(j + 3) * H_ + t];
    float k30 = WK3[(j + 0) * H_ + t], k31 = WK3[(j + 1) * H_ + t];
    float k32 = WK3[(j + 2) * H_ + t], k33 = WK3[(j + 3) * H_ + t];
    float v30 = WV3[(j + 0) * H_ + t], v31 = WV3[(j + 1) * H_ + t];
    float v32 = WV3[(j + 2) * H_ + t], v33 = WV3[(j + 3) * H_ + t];
    #pragma unroll
    for (int u = 0; u < NT; u++) {
      float4 a = ((const float4*)(xs1 + u * H_))[j4];
      float4 b = ((const float4*)(xs2 + u * H_))[j4];
      float4 c = ((const float4*)(xs3 + u * H_))[j4];
      aKb[u] = fmaf(a.x, k20, fmaf(a.y, k21, fmaf(a.z, k22, fmaf(a.w, k23, aKb[u]))));
      aKb[u] = fmaf(b.x, k30, fmaf(b.y, k31, fmaf(b.z, k32, fmaf(b.w, k33, aKb[u]))));
      aVb[u] = fmaf(a.x, v20, fmaf(a.y, v21, fmaf(a.z, v22, fmaf(a.w, v23, aVb[u]))));
      aVb[u] = fmaf(b.x, v30, fmaf(b.y, v31, fmaf(b.z, v32, fmaf(b.w, v33, aVb[u]))));
      aKe[u] = fmaf(c.x, k30, fmaf(c.y, k31, fmaf(c.z, k32, fmaf(c.w, k33, aKe[u]))));
      aVe[u] = fmaf(c.x, v30, fmaf(c.y, v31, fmaf(c.z, v32, fmaf(c.w, v33, aVe[u]))));
    }
  }
  #pragma unroll
  for (int u = 0; u < NT; u++) {
    size_t g = (size_t)(n0 + u) * H_ + t;
    nKb[g] = aKb[u]; nVb[g] = aVb[u]; nKe[g] = aKe[u]; nVe[g] = aVe[u];
  }
}

// ---------------- weight-fragment prep for FFN W1 (128x512) / W2 (512x128) ----------------
__global__ __launch_bounds__(256) void prep_wfrag2_kernel(const float* __restrict__ eW1,
    const float* __restrict__ eW2, const float* __restrict__ dW1, const float* __restrict__ dW2,
    ushort_t* __restrict__ hiOut, ushort_t* __restrict__ loOut) {
  int m = blockIdx.x;  // 0..11: eW1 l0-2, eW2 l0-2, dW1 l0-2, dW2 l0-2
  const float* W; int C;
  if (m < 3)      { W = eW1 + (size_t)m * FRAG2_;       C = 4 * H_; }
  else if (m < 6) { W = eW2 + (size_t)(m - 3) * FRAG2_; C = H_; }
  else if (m < 9) { W = dW1 + (size_t)(m - 6) * FRAG2_; C = 4 * H_; }
  else            { W = dW2 + (size_t)(m - 9) * FRAG2_; C = H_; }
  ushort_t* hi = hiOut + (size_t)m * FRAG2_;
  ushort_t* lo = loOut + (size_t)m * FRAG2_;
  int ntn = C >> 4;
  int cshift = (C == 512) ? 9 : 7;
  for (int i = 0; i < FRAG2_ / 256; i++) {
    int lin = i * 256 + threadIdx.x;
    int k = lin >> cshift, c = lin & (C - 1);
    float x = W[lin];
    int ks = k >> 5, gk = (k >> 3) & 3, j = k & 7;
    int nt = c >> 4, cc = c & 15;
    int lane = gk * 16 + cc;
    int oidx = ((ks * ntn + nt) * 64 + lane) * 8 + j;
    ushort_t hb = bf16rn(x);
    hi[oidx] = hb;
    lo[oidx] = bf16rn(x - bf16tof(hb));
  }
}

// ---------------- fused graph attention + residual LN — 4 nodes/block, stage-in-scores ----------------
// R12 (best): 8 nodes/block weight amortization, hE read 2x from global. R13 (regressed):
// separate LDS stage serialized loads vs compute and LDS 45.6KB halved occupancy. R14: the
// scores loop already reads every hE element exactly once (group g covers rows k%4==g,
// lane-strided cols) -> ALSO write those registers to an LDS tile during scores (no extra
// pass, no serialization), agg reads LDS. ANT_=4 keeps total LDS at R12's ~30KB. Per-node
// arithmetic orders identical to R12 -> bit-identical output.
constexpr int ANT_ = 4;
template<bool ENC>
__global__ __launch_bounds__(128) void attn_kernel(const float* __restrict__ hV_in,
    const float* __restrict__ hE, const int* __restrict__ E_idx, const float* __restrict__ mask,
    const float* __restrict__ WQ, const float* __restrict__ WK1T, const float* __restrict__ WV1,
    const float* __restrict__ WO,
    const float* __restrict__ nKb, const float* __restrict__ nVb,
    const float* __restrict__ nKe, const float* __restrict__ nVe,
    float* __restrict__ hV_out) {
  const int node0 = blockIdx.x * ANT_;
  const int b = node0 / N_;
  const int nbase = node0 % N_;          // all 4 nodes share batch b (N_ % ANT_ == 0)
  const int t = threadIdx.x;
  const int g = t >> 5, lane32 = t & 31;
  const int head = g;

  __shared__ __attribute__((aligned(16))) float heb[K_ * H_];        // one node's hE tile
  __shared__ __attribute__((aligned(16))) float x0s[ANT_][H_];
  __shared__ __attribute__((aligned(16))) float qs[ANT_][H_];        // q, later ob
  __shared__ __attribute__((aligned(16))) float qkagg[ANT_][4 * H_]; // qk, later agg
  __shared__ float scb[ANT_][NH_ * 32];                              // scores/att, later r
  __shared__ int nbs[ANT_][K_];
  __shared__ float mis[ANT_];
  __shared__ float mst[ANT_], ist[ANT_];

  // stage x0, neighbor lists, masks; pad score slots
  #pragma unroll
  for (int u = 0; u < ANT_; u++) {
    x0s[u][t] = hV_in[(size_t)(node0 + u) * H_ + t];
    if ((t & 31) >= K_) scb[u][t] = NEG_INF_;
  }
  if (t < ANT_ * K_) nbs[t / K_][t % K_] = E_idx[(size_t)node0 * K_ + t];
  if (t < ANT_) mis[t] = mask[(size_t)b * N_ + nbase + t];
  __syncthreads();

  // q = x0 @ WQ  (weights read once per block; per-node fmaf order = R7)
  {
    float qv[ANT_];
    #pragma unroll
    for (int u = 0; u < ANT_; u++) qv[u] = 0.f;
    for (int j4 = 0; j4 < H_ / 4; j4++) {
      int j = j4 * 4;
      float w0 = WQ[(j + 0) * H_ + t], w1 = WQ[(j + 1) * H_ + t];
      float w2 = WQ[(j + 2) * H_ + t], w3 = WQ[(j + 3) * H_ + t];
      #pragma unroll
      for (int u = 0; u < ANT_; u++) {
        float4 xv = ((const float4*)x0s[u])[j4];
        qv[u] = fmaf(xv.x, w0, fmaf(xv.y, w1, fmaf(xv.z, w2, fmaf(xv.w, w3, qv[u]))));
      }
    }
    #pragma unroll
    for (int u = 0; u < ANT_; u++) qs[u][t] = qv[u];
  }
  __syncthreads();

  // qk[h][t] = sum_{c in head h} WK1T[c*H+t] * q[c]  (per-node order = R7)
  {
    float ak[ANT_][4];
    #pragma unroll
    for (int u = 0; u < ANT_; u++)
      #pragma unroll
      for (int h = 0; h < 4; h++) ak[u][h] = 0.f;
    for (int c = 0; c < 32; c++) {
      float wA = WK1T[(c      ) * H_ + t];
      float wB = WK1T[(c + 32 ) * H_ + t];
      float wC = WK1T[(c + 64 ) * H_ + t];
      float wD = WK1T[(c + 96 ) * H_ + t];
      #pragma unroll
      for (int u = 0; u < ANT_; u++) {
        ak[u][0] = fmaf(wA, qs[u][c      ], ak[u][0]);
        ak[u][1] = fmaf(wB, qs[u][c + 32 ], ak[u][1]);
        ak[u][2] = fmaf(wC, qs[u][c + 64 ], ak[u][2]);
        ak[u][3] = fmaf(wD, qs[u][c + 96 ], ak[u][3]);
      }
    }
    #pragma unroll
    for (int u = 0; u < ANT_; u++)
      #pragma unroll
      for (int h = 0; h < 4; h++) qkagg[u][h * H_ + t] = ak[u][h];
  }
  __syncthreads();

  // per-node pipeline: scores_u (reads global hE once, tees into LDS) -> softmax_u -> agg_u (LDS)
  float onode[ANT_];
  const float scale = 0.17677669529663687f;  // 1/sqrt(32)
  #pragma unroll 1
  for (int u = 0; u < ANT_; u++) {
    const float* heu = hE + (size_t)(node0 + u) * (K_ * H_);
    const float mi = mis[u];
    const int nmod = nbase + u;
    // ---- scores_u: group g handles edges k = g, g+4, ...; tee hE values into heb
    {
      float qkv[4][4];
      #pragma unroll
      for (int h = 0; h < 4; h++)
        #pragma unroll
        for (int j = 0; j < 4; j++)
          qkv[h][j] = qkagg[u][h * H_ + lane32 + 32 * j];
      float qv[4];
      #pragma unroll
      for (int h = 0; h < 4; h++) qv[h] = qs[u][lane32 + 32 * h];
      #pragma unroll 1
      for (int kk = 0; kk < 8; kk++) {
        int k = g + 4 * kk;
        if (k >= K_) break;
        int nb = nbs[u][k];
        size_t nbg = (size_t)(b * N_ + nb) * H_ + lane32;
        float gbv[4], gev[4], m2;
        gbv[0] = nKb[nbg]; gbv[1] = nKb[nbg + 32]; gbv[2] = nKb[nbg + 64]; gbv[3] = nKb[nbg + 96];
        if (!ENC) {
          gev[0] = nKe[nbg]; gev[1] = nKe[nbg + 32]; gev[2] = nKe[nbg + 64]; gev[3] = nKe[nbg + 96];
        } else {
          m2 = mi * mask[b * N_ + nb];
        }
        const float* he = heu + k * H_;
        float he0 = he[lane32], he1 = he[lane32 + 32], he2 = he[lane32 + 64], he3 = he[lane32 + 96];
        heb[k * H_ + lane32]      = he0;
        heb[k * H_ + lane32 + 32] = he1;
        heb[k * H_ + lane32 + 64] = he2;
        heb[k * H_ + lane32 + 96] = he3;
        float pr[4];
        #pragma unroll
        for (int h = 0; h < 4; h++) {
          float ep = fmaf(qkv[h][0], he0,
                     fmaf(qkv[h][1], he1,
                     fmaf(qkv[h][2], he2, qkv[h][3] * he3)));
          if (ENC) {
            pr[h] = fmaf(qv[h], gbv[h], ep);
          } else {
            float ar = (nb < nmod) ? 1.f : 0.f;
            float bw = mi * ar, fw = mi * (1.f - ar);
            float nodek = fmaf(bw, gbv[h], fw * gev[h]);
            pr[h] = fmaf(mi, ep, qv[h] * nodek);
          }
        }
        #pragma unroll
        for (int off = 16; off > 0; off >>= 1)
          #pragma unroll
          for (int h = 0; h < 4; h++)
            pr[h] += __shfl_xor(pr[h], off, 32);
        if (lane32 == 0) {
          #pragma unroll
          for (int h = 0; h < 4; h++) {
            if (ENC) scb[u][h * 32 + k] = (m2 > 0.f) ? pr[h] * scale : NEG_INF_;
            else     scb[u][h * 32 + k] = pr[h] * scale;
          }
        }
      }
    }
    __syncthreads();
    // ---- softmax_u (= R7 per node)
    {
      float s = scb[u][t];
      float mx = s;
      #pragma unroll
      for (int off = 16; off > 0; off >>= 1) mx = fmaxf(mx, __shfl_xor(mx, off, 32));
      float ev = expf(s - mx);
      float sum = ev;
      #pragma unroll
      for (int off = 16; off > 0; off >>= 1) sum += __shfl_xor(sum, off, 32);
      scb[u][t] = ev / sum;
    }
    __syncthreads();
    // ---- agg_u: reads LDS tile; k order = R7
    {
      float a0 = 0.f, a1 = 0.f, a2 = 0.f, a3 = 0.f;
      #pragma unroll
      for (int k = 0; k < K_; k++) {
        float hv = heb[k * H_ + t];
        a0 = fmaf(scb[u][0 * 32 + k], hv, a0);
        a1 = fmaf(scb[u][1 * 32 + k], hv, a1);
        a2 = fmaf(scb[u][2 * 32 + k], hv, a2);
        a3 = fmaf(scb[u][3 * 32 + k], hv, a3);
      }
      qkagg[u][0 * H_ + t] = a0;
      qkagg[u][1 * H_ + t] = a1;
      qkagg[u][2 * H_ + t] = a2;
      qkagg[u][3 * H_ + t] = a3;
    }
    // ---- onode_u with KT=10 batching (= R7)
    {
      float on = 0.f;
      for (int kt = 0; kt < K_; kt += 10) {
        float gv[10], gve[10];
        #pragma unroll
        for (int i = 0; i < 10; i++) {
          int nb = nbs[u][kt + i];
          size_t nbg = (size_t)(b * N_ + nb) * H_ + t;
          gv[i] = nVb[nbg];
          if (!ENC) gve[i] = nVe[nbg];
        }
        #pragma unroll
        for (int i = 0; i < 10; i++) {
          int k = kt + i;
          float att = scb[u][head * 32 + k];
          if (ENC) {
            on = fmaf(att, gv[i], on);
          } else {
            int nb = nbs[u][k];
            float ar = (nb < nmod) ? 1.f : 0.f;
            float bw = mi * ar, fw = mi * (1.f - ar);
            on = fmaf(att, fmaf(bw, gv[i], fw * gve[i]), on);
          }
        }
      }
      onode[u] = on;
    }
    __syncthreads();  // heb WAR before next node's scores tee
  }

  // oe[t] = agg_{head} @ WV1[:, t]  (weights once per block; f order = R7)
  float oreg[ANT_];
  {
    float oe[ANT_];
    #pragma unroll
    for (int u = 0; u < ANT_; u++) oe[u] = 0.f;
    for (int f = 0; f < H_; f++) {
      float wv = WV1[f * H_ + t];
      #pragma unroll
      for (int u = 0; u < ANT_; u++)
        oe[u] = fmaf(qkagg[u][head * H_ + f], wv, oe[u]);
    }
    #pragma unroll
    for (int u = 0; u < ANT_; u++)
      oreg[u] = ENC ? (oe[u] + onode[u]) : fmaf(mis[u], oe[u], onode[u]);
  }
  #pragma unroll
  for (int u = 0; u < ANT_; u++) qs[u][t] = oreg[u];   // ob (qs dead after scores)
  __syncthreads();

  // dh = ob @ WO (weights once per block; j4 order = R7); residual
  float rv[ANT_];
  {
    float dh[ANT_];
    #pragma unroll
    for (int u = 0; u < ANT_; u++) dh[u] = 0.f;
    for (int j4 = 0; j4 < H_ / 4; j4++) {
      int j = j4 * 4;
      float w0 = WO[(j + 0) * H_ + t], w1 = WO[(j + 1) * H_ + t];
      float w2 = WO[(j + 2) * H_ + t], w3 = WO[(j + 3) * H_ + t];
      #pragma unroll
      for (int u = 0; u < ANT_; u++) {
        float4 ov = ((const float4*)qs[u])[j4];
        dh[u] = fmaf(ov.x, w0, fmaf(ov.y, w1, fmaf(ov.z, w2, fmaf(ov.w, w3, dh[u]))));
      }
    }
    #pragma unroll
    for (int u = 0; u < ANT_; u++) rv[u] = x0s[u][t] + dh[u];
  }
  #pragma unroll
  for (int u = 0; u < ANT_; u++) scb[u][t] = rv[u];    // r rows (scb dead after onode)
  __syncthreads();

  // row LN stats: 32 threads per node-row
  {
    int u = t >> 5, li = t & 31;
    float s = 0.f;
    #pragma unroll
    for (int i = 0; i < 4; i++) s += scb[u][li + 32 * i];
    s += __shfl_xor(s, 1, 64); s += __shfl_xor(s, 2, 64);
    s += __shfl_xor(s, 4, 64); s += __shfl_xor(s, 8, 64); s += __shfl_xor(s, 16, 64);
    float mean = s * (1.f / H_);
    float vs = 0.f;
    #pragma unroll
    for (int i = 0; i < 4; i++) {
      float d = scb[u][li + 32 * i] - mean;
      vs = fmaf(d, d, vs);
    }
    vs += __shfl_xor(vs, 1, 64); vs += __shfl_xor(vs, 2, 64);
    vs += __shfl_xor(vs, 4, 64); vs += __shfl_xor(vs, 8, 64); vs += __shfl_xor(vs, 16, 64);
    if (li == 0) { mst[u] = mean; ist[u] = rsqrtf(vs * (1.f / H_) + 1e-6f); }
  }
  __syncthreads();
  #pragma unroll
  for (int u = 0; u < ANT_; u++)
    hV_out[(size_t)(node0 + u) * H_ + t] = (rv[u] - mst[u]) * ist[u];
}

// ---------------- FFN via split-bf16 MFMA: LN(x + relu(x@W1+b1)@W2+b2) * mask ----------------
constexpr int NTF_ = 8;
__global__ __launch_bounds__(128) void ffn_kernel(float* __restrict__ hV, const float* __restrict__ mask,
    const ushort_t* __restrict__ w1hi, const ushort_t* __restrict__ w1lo,
    const ushort_t* __restrict__ w2hi, const ushort_t* __restrict__ w2lo,
    const float* __restrict__ b1, const float* __restrict__ b2) {
  int n0 = blockIdx.x * NTF_, t = threadIdx.x;
  const int w = t >> 6, l = t & 63, c0 = l & 15, g = l >> 4;
  __shared__ __attribute__((aligned(16))) ushort_t xhi[16 * H_], xlo[16 * H_];
  __shared__ __attribute__((aligned(16))) ushort_t hpl[2][2 * 16 * H_];
  __shared__ float mst[16], ist[16];
  float* obuf = (float*)&hpl[0][0];

  #pragma unroll
  for (int it = 0; it < 2; it++) {
    int id = it * 128 + t;
    int r = id >> 4, u = id & 15;
    short8 h8 = {0,0,0,0,0,0,0,0}, l8 = {0,0,0,0,0,0,0,0};
    if (r < NTF_) {
      const float4* p = (const float4*)(hV + (size_t)(n0 + r) * H_ + u * 8);
      float4 f0 = p[0], f1 = p[1];
      float xv[8] = {f0.x, f0.y, f0.z, f0.w, f1.x, f1.y, f1.z, f1.w};
      #pragma unroll
      for (int e = 0; e < 8; e++) {
        ushort_t hb = bf16rn(xv[e]);
        h8[e] = (short)hb;
        l8[e] = (short)bf16rn(xv[e] - bf16tof(hb));
      }
    }
    int us = u ^ (r & 15);
    *(short8*)&xhi[r * 128 + us * 8] = h8;
    *(short8*)&xlo[r * 128 + us * 8] = l8;
  }
  __syncthreads();

  short8 axh[4], axl[4];
  #pragma unroll
  for (int ks = 0; ks < 4; ks++) {
    int us = ((ks * 4 + g) ^ c0) * 8;
    axh[ks] = *(const short8*)&xhi[c0 * 128 + us];
    axl[ks] = *(const short8*)&xlo[c0 * 128 + us];
  }

  ushort_t* myhhi = &hpl[w][0];
  ushort_t* myhlo = &hpl[w][16 * H_];
  f32x4 accO[8];
  #pragma unroll
  for (int nt = 0; nt < 8; nt++) accO[nt] = f32x4{0.f, 0.f, 0.f, 0.f};

  #pragma unroll
  for (int cc = 0; cc < 2; cc++) {
    int c = 2 * w + cc;
    f32x4 a1[8];
    #pragma unroll
    for (int nt = 0; nt < 8; nt++) a1[nt] = f32x4{0.f, 0.f, 0.f, 0.f};
    #pragma unroll
    for (int ks = 0; ks < 4; ks++) {
      #pragma unroll
      for (int nt = 0; nt < 8; nt++) {
        size_t boff = (size_t)(((ks * 32 + (c * 8 + nt)) * 64 + l) * 8);
        short8 bh = *(const short8*)(w1hi + boff);
        short8 bl = *(const short8*)(w1lo + boff);
        a1[nt] = __builtin_amdgcn_mfma_f32_16x16x32_bf16(axh[ks], bh, a1[nt], 0, 0, 0);
        a1[nt] = __builtin_amdgcn_mfma_f32_16x16x32_bf16(axl[ks], bh, a1[nt], 0, 0, 0);
        a1[nt] = __builtin_amdgcn_mfma_f32_16x16x32_bf16(axh[ks], bl, a1[nt], 0, 0, 0);
        a1[nt] = __builtin_amdgcn_mfma_f32_16x16x32_bf16(axl[ks], bl, a1[nt], 0, 0, 0);
      }
    }
    #pragma unroll
    for (int nt = 0; nt < 8; nt++) {
      int col = nt * 16 + c0;
      float bb = b1[c * 128 + col];
      #pragma unroll
      for (int j = 0; j < 4; j++) {
        int row = g * 4 + j;
        float hv = fmaxf(a1[nt][j] + bb, 0.f);
        ushort_t hb = bf16rn(hv);
        ushort_t lb = bf16rn(hv - bf16tof(hb));
        int us2 = ((col >> 3) ^ row) * 8 + (col & 7);
        myhhi[row * 128 + us2] = hb;
        myhlo[row * 128 + us2] = lb;
      }
    }
    #pragma unroll
    for (int ks = 0; ks < 4; ks++) {
      int us2 = ((ks * 4 + g) ^ c0) * 8;
      short8 ahh = *(const short8*)&myhhi[c0 * 128 + us2];
      short8 ahl = *(const short8*)&myhlo[c0 * 128 + us2];
      #pragma unroll
      for (int nt = 0; nt < 8; nt++) {
        size_t boff = (size_t)((((c * 4 + ks) * 8 + nt) * 64 + l) * 8);
        short8 bh = *(const short8*)(w2hi + boff);
        short8 bl = *(const short8*)(w2lo + boff);
        accO[nt] = __builtin_amdgcn_mfma_f32_16x16x32_bf16(ahh, bh, accO[nt], 0, 0, 0);
        accO[nt] = __builtin_amdgcn_mfma_f32_16x16x32_bf16(ahl, bh, accO[nt], 0, 0, 0);
        accO[nt] = __builtin_amdgcn_mfma_f32_16x16x32_bf16(ahh, bl, accO[nt], 0, 0, 0);
        accO[nt] = __builtin_amdgcn_mfma_f32_16x16x32_bf16(ahl, bl, accO[nt], 0, 0, 0);
      }
    }
  }

  if (w == 0) {
    #pragma unroll
    for (int nt = 0; nt < 8; nt++) {
      #pragma unroll
      for (int j = 0; j < 4; j++) {
        int row = g * 4 + j;
        if (row < NTF_) obuf[row * H_ + nt * 16 + c0] = accO[nt][j];
      }
    }
  }
  __syncthreads();
  if (w == 1) {
    #pragma unroll
    for (int nt = 0; nt < 8; nt++) {
      #pragma unroll
      for (int j = 0; j < 4; j++) {
        int row = g * 4 + j;
        if (row < NTF_) obuf[row * H_ + nt * 16 + c0] += accO[nt][j];
      }
    }
  }
  __syncthreads();

  float rv[NTF_];
  {
    int un = t >> 3, e = t & 7;
    float bb = b2[t];
    #pragma unroll
    for (int u = 0; u < NTF_; u++) {
      int us = (un ^ u) * 8 + e;
      float xr = bf16tof(xhi[u * 128 + us]) + bf16tof(xlo[u * 128 + us]);
      rv[u] = xr + obuf[u * H_ + t] + bb;
    }
  }
  #pragma unroll
  for (int u = 0; u < NTF_; u++) obuf[u * H_ + t] = rv[u];
  __syncthreads();
  {
    int row = t >> 3, li = t & 7;
    float s = 0.f;
    if (row < NTF_) {
      for (int i = 0; i < 16; i++) s += obuf[row * H_ + li + 8 * i];
    }
    s += __shfl_xor(s, 1, 64); s += __shfl_xor(s, 2, 64); s += __shfl_xor(s, 4, 64);
    float mean = s * (1.f / H_);
    float vs = 0.f;
    if (row < NTF_) {
      for (int i = 0; i < 16; i++) {
        float d = obuf[row * H_ + li + 8 * i] - mean;
        vs = fmaf(d, d, vs);
      }
    }
    vs += __shfl_xor(vs, 1, 64); vs += __shfl_xor(vs, 2, 64); vs += __shfl_xor(vs, 4, 64);
    if (li == 0 && row < NTF_) { mst[row] = mean; ist[row] = rsqrtf(vs * (1.f / H_) + 1e-6f); }
  }
  __syncthreads();
  #pragma unroll
  for (int u = 0; u < NTF_; u++) {
    float y = (rv[u] - mst[u]) * ist[u] * mask[n0 + u];
    hV[(size_t)(n0 + u) * H_ + t] = y;
  }
}

// ---------------- output: log_softmax(hV @ W_out + b_out), fp32, 2 nodes/block ----------------
__global__ __launch_bounds__(128) void out_kernel(const float* __restrict__ hV,
    const float* __restrict__ Wout, const float* __restrict__ bout, float* __restrict__ out) {
  int g = threadIdx.x >> 6, t = threadIdx.x & 63;
  int node = blockIdx.x * 2 + g;
  __shared__ float x[2][H_];
  __shared__ float lg[2][V_];
  __shared__ float lse[2];
  x[g][t] = hV[(size_t)node * H_ + t];
  x[g][t + 64] = hV[(size_t)node * H_ + t + 64];
  __syncthreads();
  if (t < V_) {
    float a = bout[t];
    for (int h = 0; h < H_; h++) a = fmaf(x[g][h], Wout[h * V_ + t], a);
    lg[g][t] = a;
  }
  __syncthreads();
  if (t == 0) {
    float mx = -3.4e38f;
    for (int v = 0; v < V_; v++) mx = fmaxf(mx, lg[g][v]);
    float s = 0.f;
    for (int v = 0; v < V_; v++) s += expf(lg[g][v] - mx);
    lse[g] = mx + logf(s);
  }
  __syncthreads();
  if (t < V_) out[(size_t)node * V_ + t] = lg[g][t] - lse[g];
}

// ---------------- host ----------------
extern "C" void kernel_launch(void* const* d_in, const int* in_sizes, int n_in,
                              void* d_out, int out_size, void* d_ws, size_t ws_size,
                              hipStream_t stream) {
  const float* X    = (const float*)d_in[0];
  const float* mask = (const float*)d_in[1];
  const int*   S    = (const int*)d_in[2];
  const float* Wfn  = (const float*)d_in[3];
  const float* bfn  = (const float*)d_in[4];
  const float* Wfe  = (const float*)d_in[5];
  const float* bfe  = (const float*)d_in[6];
  const float* Wv   = (const float*)d_in[7];
  const float* bv   = (const float*)d_in[8];
  const float* We   = (const float*)d_in[9];
  const float* be   = (const float*)d_in[10];
  const float* Ws   = (const float*)d_in[11];
  const float* eWQ  = (const float*)d_in[12];
  const float* eWK  = (const float*)d_in[13];
  const float* eWV  = (const float*)d_in[14];
  const float* eWO  = (const float*)d_in[15];
  const float* eW1  = (const float*)d_in[16];
  const float* eb1  = (const float*)d_in[17];
  const float* eW2  = (const float*)d_in[18];
  const float* eb2  = (const float*)d_in[19];
  const float* dWQ  = (const float*)d_in[20];
  const float* dWK  = (const float*)d_in[21];
  const float* dWV  = (const float*)d_in[22];
  const float* dWO  = (const float*)d_in[23];
  const float* dW1  = (const float*)d_in[24];
  const float* db1  = (const float*)d_in[25];
  const float* dW2  = (const float*)d_in[26];
  const float* db2  = (const float*)d_in[27];
  const float* Wout = (const float*)d_in[28];
  const float* bout = (const float*)d_in[29];
  float* out = (float*)d_out;

  char* w = (char*)d_ws;
  int*    eidx = (int*)w;     w += (size_t)BN_ * K_ * 4;
  float*  dnb  = (float*)w;   w += (size_t)BN_ * K_ * 4;
  float*  vf   = (float*)w;   w += (size_t)BN_ * 6 * 4;
  float*  hVa  = (float*)w;   w += (size_t)BN_ * H_ * 4;
  float*  hVb  = (float*)w;   w += (size_t)BN_ * H_ * 4;
  float*  hVc  = (float*)w;   w += (size_t)BN_ * H_ * 4;
  float*  nKb  = (float*)w;   w += (size_t)BN_ * H_ * 4;
  float*  nVb  = (float*)w;   w += (size_t)BN_ * H_ * 4;
  float*  nKe  = (float*)w;   w += (size_t)BN_ * H_ * 4;
  float*  nVe  = (float*)w;   w += (size_t)BN_ * H_ * 4;
  float*  hE   = (float*)w;   w += (size_t)BN_ * K_ * H_ * 4;
  float*  wkt  = (float*)w;   w += (size_t)6 * FRAG_ * 4;       // WK1^T, 6 layers
  ushort_t* wf2Hi = (ushort_t*)w; w += (size_t)12 * FRAG2_ * 2;
  ushort_t* wf2Lo = (ushort_t*)w; w += (size_t)12 * FRAG2_ * 2;
  ushort_t* feHi = (ushort_t*)w; w += (size_t)4096 * 2;
  ushort_t* feLo = (ushort_t*)w; w += (size_t)4096 * 2;
  ushort_t* weHi = (ushort_t*)w; w += (size_t)FRAG_ * 2;
  ushort_t* weLo = (ushort_t*)w; w += (size_t)FRAG_ * 2;

  topk_kernel<<<BN_ / TQ_, 256, 0, stream>>>(X, mask, eidx, dnb);
  dihedral_kernel<<<(BN_ + 255) / 256, 256, 0, stream>>>(X, vf);
  node_embed_kernel<<<BN_, H_, 0, stream>>>(vf, Wfn, bfn, Wv, bv, hVa);
  prep_edge_w_kernel<<<2, 256, 0, stream>>>(Wfe, We, feHi, feLo, weHi, weLo);
  edge_embed_kernel<<<BN_ * K_ / EEB_, 128, 0, stream>>>(eidx, dnb, feHi, feLo, bfe, weHi, weLo, be, hE);
  prep_wkt_kernel<<<6, 256, 0, stream>>>(eWK, dWK, wkt);
  prep_wfrag2_kernel<<<12, 256, 0, stream>>>(eW1, eW2, dW1, dW2, wf2Hi, wf2Lo);

  // encoder: a->b, b->a, a->b
  float* cur = hVa; float* nxt = hVb;
  for (int l = 0; l < 3; l++) {
    const float* WK = eWK + (size_t)l * 2 * H_ * H_;
    const float* WV = eWV + (size_t)l * 2 * H_ * H_;
    node_proj_kernel<<<BN_ / 16, H_, 0, stream>>>(cur,
        WK + (size_t)H_ * H_, WV + (size_t)H_ * H_, nKb, nVb);
    attn_kernel<true><<<BN_ / ANT_, 128, 0, stream>>>(cur, hE, eidx, mask,
        eWQ + (size_t)l * H_ * H_,
        wkt + (size_t)l * FRAG_,
        WV,                               // WV1: first HxH block, original layout
        eWO + (size_t)l * H_ * H_,
        nKb, nVb, nullptr, nullptr, nxt);
    ffn_kernel<<<BN_ / NTF_, 128, 0, stream>>>(nxt, mask,
        wf2Hi + (size_t)l * FRAG2_, wf2Lo + (size_t)l * FRAG2_,
        wf2Hi + (size_t)(3 + l) * FRAG2_, wf2Lo + (size_t)(3 + l) * FRAG2_,
        eb1 + (size_t)l * 4 * H_, eb2 + (size_t)l * H_);
    float* tmp = cur; cur = nxt; nxt = tmp;
  }
  float* henc = cur;  // = hVb
  // decoder: henc->a, a->c, c->a (henc preserved)
  float* din = henc;
  float* douts[3] = { hVa, hVc, hVa };
  for (int l = 0; l < 3; l++) {
    const float* WK = dWK + (size_t)l * 3 * H_ * H_;
    const float* WV = dWV + (size_t)l * 3 * H_ * H_;
    node_proj3_kernel<<<BN_ / 8, H_, 0, stream>>>(S, Ws, din, henc,
        WK + (size_t)H_ * H_, WV + (size_t)H_ * H_,
        WK + (size_t)2 * H_ * H_, WV + (size_t)2 * H_ * H_,
        nKb, nVb, nKe, nVe);
    attn_kernel<false><<<BN_ / ANT_, 128, 0, stream>>>(din, hE, eidx, mask,
        dWQ + (size_t)l * H_ * H_,
        wkt + (size_t)(3 + l) * FRAG_,
        WV,                               // WV1: first HxH block, original layout
        dWO + (size_t)l * H_ * H_,
        nKb, nVb, nKe, nVe, douts[l]);
    ffn_kernel<<<BN_ / NTF_, 128, 0, stream>>>(douts[l], mask,
        wf2Hi + (size_t)(6 + l) * FRAG2_, wf2Lo + (size_t)(6 + l) * FRAG2_,
        wf2Hi + (size_t)(9 + l) * FRAG2_, wf2Lo + (size_t)(9 + l) * FRAG2_,
        db1 + (size_t)l * 4 * H_, db2 + (size_t)l * H_);
    din = douts[l];
  }
  out_kernel<<<BN_ / 2, 128, 0, stream>>>(din, Wout, bout, out);
}

// Round 15
// 1420.474 us; speedup vs baseline: 1.4218x; 1.1290x over previous
//
#include <hip/hip_runtime.h>
#include <hip/hip_bf16.h>
#include <math.h>

#define DEVFN __device__ __forceinline__

constexpr int B_ = 16, N_ = 512, K_ = 30, H_ = 128;
constexpr int NH_ = 4, V_ = 20;
constexpr int BN_ = B_ * N_;
constexpr float NEG_INF_ = -3.4028235e38f;
constexpr int FRAG_ = H_ * H_;        // 16384 elems per 128x128 plane
constexpr int FRAG2_ = H_ * 4 * H_;   // 65536 elems per 128x512 / 512x128 plane

typedef unsigned short ushort_t;
using short8 = __attribute__((ext_vector_type(8))) short;
using f32x4  = __attribute__((ext_vector_type(4))) float;

DEVFN ushort_t bf16rn(float x) {
  unsigned u = __float_as_uint(x);
  return (ushort_t)((u + 0x7fffu + ((u >> 16) & 1u)) >> 16);
}
DEVFN float bf16tof(ushort_t h) { return __uint_as_float(((unsigned)h) << 16); }

// ---------------- top-K neighbors: distances BIT-EXACT to plain numpy float32 ----------------
// DO NOT TOUCH the distance math / tie-break. R6 rewrite: register-resident selection,
// 4 queries/block (1 wave each); zero barriers/LDS in the K-loop. Bit-identical output.
constexpr int TQ_ = 4;
__global__ __launch_bounds__(256) void topk_kernel(const float* __restrict__ X,
    const float* __restrict__ mask, int* __restrict__ E_idx, float* __restrict__ Dnb) {
  __shared__ float xs[N_ * 3];
  __shared__ float ms[N_];
  int blk = blockIdx.x;
  int b = blk / (N_ / TQ_);
  int i0 = (blk % (N_ / TQ_)) * TQ_;
  int t = threadIdx.x;
  int wv = t >> 6, l = t & 63;
  for (int j = t; j < N_; j += 256) {
    const float* p = X + ((size_t)(b * N_ + j) * 4 + 1) * 3;  // CA atom
    xs[j * 3 + 0] = p[0]; xs[j * 3 + 1] = p[1]; xs[j * 3 + 2] = p[2];
    ms[j] = mask[b * N_ + j];
  }
  __syncthreads();
  const int i = i0 + wv;
  const float xi0 = xs[i * 3], xi1 = xs[i * 3 + 1], xi2 = xs[i * 3 + 2];
  const float mi = ms[i];
  float D[8];
  float lmax = -3.4e38f;
  #pragma unroll
  for (int e = 0; e < 8; e++) {
    int j = l * 8 + e;
    float dx = __fsub_rn(xi0, xs[j * 3]);
    float dy = __fsub_rn(xi1, xs[j * 3 + 1]);
    float dz = __fsub_rn(xi2, xs[j * 3 + 2]);
    float m2 = __fmul_rn(mi, ms[j]);
    float s = __fadd_rn(__fadd_rn(__fadd_rn(__fmul_rn(dx, dx), __fmul_rn(dy, dy)),
                                  __fmul_rn(dz, dz)), 1e-6f);
    float Dv = __fmul_rn(m2, __fsqrt_rn(s));
    D[e] = Dv;
    lmax = fmaxf(lmax, Dv);
  }
  #pragma unroll
  for (int off = 32; off > 0; off >>= 1) lmax = fmaxf(lmax, __shfl_xor(lmax, off, 64));
  unsigned long long key[8];
  unsigned long long lmin = ~0ull;
  #pragma unroll
  for (int e = 0; e < 8; e++) {
    int j = l * 8 + e;
    float m2 = __fmul_rn(mi, ms[j]);
    float d = __fadd_rn(D[e], __fmul_rn(__fsub_rn(1.f, m2), lmax));
    unsigned long long k = (((unsigned long long)__float_as_uint(d)) << 32)
                         | (unsigned)(N_ - 1 - j);
    key[e] = k;
    if (k < lmin) lmin = k;
  }
  for (int kk = 0; kk < K_; kk++) {
    unsigned long long m = lmin;
    #pragma unroll
    for (int off = 32; off > 0; off >>= 1) {
      unsigned long long o = __shfl_xor(m, off, 64);
      if (o < m) m = o;
    }
    int j = N_ - 1 - (int)(m & 0xffffffffull);
    if (l == 0) {
      E_idx[(size_t)(b * N_ + i) * K_ + kk] = j;
      Dnb[(size_t)(b * N_ + i) * K_ + kk] = __uint_as_float((unsigned)(m >> 32));
    }
    if ((j >> 3) == l) {
      key[j & 7] = ~0ull;
      unsigned long long nm = key[0];
      #pragma unroll
      for (int e = 1; e < 8; e++) if (key[e] < nm) nm = key[e];
      lmin = nm;
    }
  }
}

// ---------------- dihedral features (1 thread / node), fp32 ----------------
DEVFN void load_atom(const float* X, int b, int m, float* p) {
  const float* q = X + ((size_t)(b * N_ + m / 3) * 4 + (m % 3)) * 3;
  p[0] = q[0]; p[1] = q[1]; p[2] = q[2];
}
DEVFN void cross3(const float* a, const float* b, float* c) {
  c[0] = a[1] * b[2] - a[2] * b[1];
  c[1] = a[2] * b[0] - a[0] * b[2];
  c[2] = a[0] * b[1] - a[1] * b[0];
}
DEVFN void norm3(float* v) {
  float n = sqrtf(v[0] * v[0] + v[1] * v[1] + v[2] * v[2]) + 1e-7f;
  v[0] /= n; v[1] /= n; v[2] /= n;
}
__global__ __launch_bounds__(256) void dihedral_kernel(const float* __restrict__ X, float* __restrict__ Vf) {
  int idx = blockIdx.x * blockDim.x + threadIdx.x;
  if (idx >= BN_) return;
  int b = idx / N_, n = idx % N_;
  float cs[3], sn[3];
  for (int s = 0; s < 3; s++) {
    int p = 3 * n + s;
    float a = 0.f;
    if (p >= 1 && p <= 3 * N_ - 3) {
      int tt = p - 1;
      float u[3][3], prev[3], cur[3];
      load_atom(X, b, tt, prev);
      for (int q = 0; q < 3; q++) {
        load_atom(X, b, tt + q + 1, cur);
        float d0 = cur[0] - prev[0], d1 = cur[1] - prev[1], d2 = cur[2] - prev[2];
        float nr = sqrtf(d0 * d0 + d1 * d1 + d2 * d2) + 1e-7f;
        u[q][0] = d0 / nr; u[q][1] = d1 / nr; u[q][2] = d2 / nr;
        prev[0] = cur[0]; prev[1] = cur[1]; prev[2] = cur[2];
      }
      float n2v[3], n1v[3];
      cross3(u[0], u[1], n2v); norm3(n2v);
      cross3(u[1], u[2], n1v); norm3(n1v);
      float cd = n2v[0] * n1v[0] + n2v[1] * n1v[1] + n2v[2] * n1v[2];
      cd = fminf(fmaxf(cd, -1.f + 1e-7f), 1.f - 1e-7f);
      float dt = u[0][0] * n1v[0] + u[0][1] * n1v[1] + u[0][2] * n1v[2];
      float sg = (dt > 0.f) ? 1.f : ((dt < 0.f) ? -1.f : 0.f);
      a = sg * acosf(cd);
    }
    cs[s] = cosf(a); sn[s] = sinf(a);
  }
  float* o = Vf + (size_t)idx * 6;
  o[0] = cs[0]; o[1] = cs[1]; o[2] = cs[2]; o[3] = sn[0]; o[4] = sn[1]; o[5] = sn[2];
}

// ---------------- node embed: hV = LN(V@Wfn+bfn) @ Wv + bv (fp32, shuffle-LN) ----------------
__global__ __launch_bounds__(H_) void node_embed_kernel(const float* __restrict__ Vf,
    const float* __restrict__ Wfn, const float* __restrict__ bfn,
    const float* __restrict__ Wv, const float* __restrict__ bv, float* __restrict__ hV) {
  int node = blockIdx.x, t = threadIdx.x;
  const int w = t >> 6, l = t & 63;
  __shared__ float v6[6];
  __shared__ __attribute__((aligned(16))) float t1[H_];
  __shared__ float wred[2];
  if (t < 6) v6[t] = Vf[(size_t)node * 6 + t];
  __syncthreads();
  float acc = bfn[t];
  for (int f = 0; f < 6; f++) acc = fmaf(v6[f], Wfn[f * H_ + t], acc);
  float s1 = acc;
  #pragma unroll
  for (int off = 32; off > 0; off >>= 1) s1 += __shfl_xor(s1, off, 64);
  if (l == 0) wred[w] = s1;
  __syncthreads();
  float mean = (wred[0] + wred[1]) * (1.f / H_);
  float d0 = acc - mean;
  float s2 = d0 * d0;
  #pragma unroll
  for (int off = 32; off > 0; off >>= 1) s2 += __shfl_xor(s2, off, 64);
  __syncthreads();
  if (l == 0) wred[w] = s2;
  __syncthreads();
  float var = (wred[0] + wred[1]) * (1.f / H_);
  t1[t] = d0 * rsqrtf(var + 1e-6f);
  __syncthreads();
  float o = bv[t];
  for (int j4 = 0; j4 < H_ / 4; j4++) {
    float4 xv = ((const float4*)t1)[j4];
    int j = j4 * 4;
    o = fmaf(xv.x, Wv[(j + 0) * H_ + t],
        fmaf(xv.y, Wv[(j + 1) * H_ + t],
        fmaf(xv.z, Wv[(j + 2) * H_ + t],
        fmaf(xv.w, Wv[(j + 3) * H_ + t], o))));
  }
  hV[(size_t)node * H_ + t] = o;
}

// ---------------- prep Wfe (32x128) + We (128x128) -> MFMA B-frag bf16 hi/lo ----------------
__global__ __launch_bounds__(256) void prep_edge_w_kernel(const float* __restrict__ Wfe,
    const float* __restrict__ We, ushort_t* __restrict__ feHi, ushort_t* __restrict__ feLo,
    ushort_t* __restrict__ weHi, ushort_t* __restrict__ weLo) {
  if (blockIdx.x == 0) {
    for (int i = 0; i < 4096 / 256; i++) {
      int lin = i * 256 + threadIdx.x;   // k*128 + c, k<32
      int k = lin >> 7, c = lin & 127;
      float x = Wfe[lin];
      int gk = k >> 3, j = k & 7;
      int nt = c >> 4, cc = c & 15;
      int oidx = (nt * 64 + gk * 16 + cc) * 8 + j;
      ushort_t hb = bf16rn(x);
      feHi[oidx] = hb;
      feLo[oidx] = bf16rn(x - bf16tof(hb));
    }
  } else {
    for (int i = 0; i < FRAG_ / 256; i++) {
      int lin = i * 256 + threadIdx.x;
      int k = lin >> 7, c = lin & 127;
      float x = We[lin];
      int ks = k >> 5, gk = (k >> 3) & 3, j = k & 7;
      int nt = c >> 4, cc = c & 15;
      int oidx = ((ks * 8 + nt) * 64 + gk * 16 + cc) * 8 + j;
      ushort_t hb = bf16rn(x);
      weHi[oidx] = hb;
      weLo[oidx] = bf16rn(x - bf16tof(hb));
    }
  }
}

// ---------------- prep WK1T: transpose first HxH block of attn K-weights (fp32) ----------------
__global__ __launch_bounds__(256) void prep_wkt_kernel(const float* __restrict__ eWK,
    const float* __restrict__ dWK, float* __restrict__ outT) {
  int m = blockIdx.x;  // 0..2 enc, 3..5 dec
  const float* W = (m < 3) ? (eWK + (size_t)m * 2 * H_ * H_)
                           : (dWK + (size_t)(m - 3) * 3 * H_ * H_);
  float* o = outT + (size_t)m * FRAG_;
  for (int i = 0; i < FRAG_ / 256; i++) {
    int lin = i * 256 + threadIdx.x;   // lin = c*H + f (coalesced write)
    int c = lin >> 7, f = lin & 127;
    o[lin] = W[f * H_ + c];
  }
}

// ---------------- edge embed via split-bf16 MFMA: hE = LN(E@Wfe+bfe) @ We + be ----------------
constexpr int EEB_ = 32;
constexpr int FPS_ = 40;   // feats plane stride in shorts
__global__ __launch_bounds__(128) void edge_embed_kernel(const int* __restrict__ E_idx,
    const float* __restrict__ Dnb,
    const ushort_t* __restrict__ feHi, const ushort_t* __restrict__ feLo,
    const float* __restrict__ bfe,
    const ushort_t* __restrict__ weHi, const ushort_t* __restrict__ weLo,
    const float* __restrict__ be, float* __restrict__ hE) {
  int e0 = blockIdx.x * EEB_, t = threadIdx.x;
  const int w = t >> 6, l = t & 63, c0 = l & 15, g = l >> 4;
  __shared__ ushort_t fhi[EEB_ * FPS_], flo[EEB_ * FPS_];
  __shared__ __attribute__((aligned(16))) char sbuf[EEB_ * H_ * 4];
  float* buf = (float*)sbuf;
  ushort_t* p2hi = (ushort_t*)sbuf;
  ushort_t* p2lo = (ushort_t*)(sbuf + EEB_ * H_ * 2);
  __shared__ float mst[EEB_], ist[EEB_];

  #pragma unroll
  for (int it = 0; it < 8; it++) {
    int id = it * 128 + t;
    int r = id >> 5, f = id & 31;
    int e = e0 + r;
    int n = (e / K_) % N_;
    float v;
    if (f < 16) {
      int jj = (f < 8) ? f : (f - 8);
      float freq = expf(-logf(10000.f) * (2.f * jj) / 16.f);
      float ang = (float)(E_idx[e] - n) * freq;
      v = (f < 8) ? cosf(ang) : sinf(ang);
    } else {
      int rr = f - 16;
      float mu = 20.f * (float)rr / 15.f;
      float z = (Dnb[e] - mu) * (1.f / 1.25f);
      v = expf(-z * z);
    }
    ushort_t hb = bf16rn(v);
    fhi[r * FPS_ + f] = hb;
    flo[r * FPS_ + f] = bf16rn(v - bf16tof(hb));
  }
  __syncthreads();

  {
    short8 ah[2], al[2];
    #pragma unroll
    for (int mt = 0; mt < 2; mt++) {
      int r = mt * 16 + c0;
      ah[mt] = *(const short8*)&fhi[r * FPS_ + g * 8];
      al[mt] = *(const short8*)&flo[r * FPS_ + g * 8];
    }
    #pragma unroll
    for (int nt = 0; nt < 4; nt++) {
      int ntg = w * 4 + nt;
      size_t boff = (size_t)((ntg * 64 + l) * 8);
      short8 bh = *(const short8*)(feHi + boff);
      short8 bl = *(const short8*)(feLo + boff);
      int c = ntg * 16 + c0;
      float bb = bfe[c];
      #pragma unroll
      for (int mt = 0; mt < 2; mt++) {
        f32x4 a = f32x4{0.f, 0.f, 0.f, 0.f};
        a = __builtin_amdgcn_mfma_f32_16x16x32_bf16(ah[mt], bh, a, 0, 0, 0);
        a = __builtin_amdgcn_mfma_f32_16x16x32_bf16(al[mt], bh, a, 0, 0, 0);
        a = __builtin_amdgcn_mfma_f32_16x16x32_bf16(ah[mt], bl, a, 0, 0, 0);
        a = __builtin_amdgcn_mfma_f32_16x16x32_bf16(al[mt], bl, a, 0, 0, 0);
        #pragma unroll
        for (int j = 0; j < 4; j++) {
          int row = mt * 16 + g * 4 + j;
          buf[row * H_ + c] = a[j] + bb;
        }
      }
    }
  }
  __syncthreads();

  {
    int row = t >> 2, li = t & 3;
    float s = 0.f;
    for (int i = 0; i < 32; i++) {
      int col = li + 4 * ((i + row) & 31);
      s += buf[row * H_ + col];
    }
    s += __shfl_xor(s, 1, 64); s += __shfl_xor(s, 2, 64);
    float mean = s * (1.f / H_);
    float vs = 0.f;
    for (int i = 0; i < 32; i++) {
      int col = li + 4 * ((i + row) & 31);
      float d = buf[row * H_ + col] - mean;
      vs = fmaf(d, d, vs);
    }
    vs += __shfl_xor(vs, 1, 64); vs += __shfl_xor(vs, 2, 64);
    if (li == 0) { mst[row] = mean; ist[row] = rsqrtf(vs * (1.f / H_) + 1e-6f); }
  }
  __syncthreads();

  float vreg[32];
  #pragma unroll
  for (int it = 0; it < 4; it++) {
    int id = it * 128 + t;
    int r = id >> 4, u = id & 15;
    float mean = mst[r], inv = ist[r];
    #pragma unroll
    for (int e2 = 0; e2 < 8; e2++) vreg[it * 8 + e2] = (buf[r * H_ + u * 8 + e2] - mean) * inv;
  }
  __syncthreads();
  #pragma unroll
  for (int it = 0; it < 4; it++) {
    int id = it * 128 + t;
    int r = id >> 4, u = id & 15;
    short8 h8, l8;
    #pragma unroll
    for (int e2 = 0; e2 < 8; e2++) {
      float x = vreg[it * 8 + e2];
      ushort_t hb = bf16rn(x);
      h8[e2] = (short)hb;
      l8[e2] = (short)bf16rn(x - bf16tof(hb));
    }
    int us = u ^ (r & 15);
    *(short8*)&p2hi[r * 128 + us * 8] = h8;
    *(short8*)&p2lo[r * 128 + us * 8] = l8;
  }
  __syncthreads();

  short8 ah2[2][4], al2[2][4];
  #pragma unroll
  for (int mt = 0; mt < 2; mt++) {
    int r = mt * 16 + c0;
    #pragma unroll
    for (int ks = 0; ks < 4; ks++) {
      int us = (ks * 4 + g) ^ c0;
      ah2[mt][ks] = *(const short8*)&p2hi[r * 128 + us * 8];
      al2[mt][ks] = *(const short8*)&p2lo[r * 128 + us * 8];
    }
  }
  f32x4 acc2[2][4];
  #pragma unroll
  for (int mt = 0; mt < 2; mt++)
    #pragma unroll
    for (int nt = 0; nt < 4; nt++) acc2[mt][nt] = f32x4{0.f, 0.f, 0.f, 0.f};
  #pragma unroll
  for (int ks = 0; ks < 4; ks++) {
    #pragma unroll
    for (int nt = 0; nt < 4; nt++) {
      int ntg = w * 4 + nt;
      size_t boff = (size_t)(((ks * 8 + ntg) * 64 + l) * 8);
      short8 bh = *(const short8*)(weHi + boff);
      short8 bl = *(const short8*)(weLo + boff);
      #pragma unroll
      for (int mt = 0; mt < 2; mt++) {
        acc2[mt][nt] = __builtin_amdgcn_mfma_f32_16x16x32_bf16(ah2[mt][ks], bh, acc2[mt][nt], 0, 0, 0);
        acc2[mt][nt] = __builtin_amdgcn_mfma_f32_16x16x32_bf16(al2[mt][ks], bh, acc2[mt][nt], 0, 0, 0);
        acc2[mt][nt] = __builtin_amdgcn_mfma_f32_16x16x32_bf16(ah2[mt][ks], bl, acc2[mt][nt], 0, 0, 0);
        acc2[mt][nt] = __builtin_amdgcn_mfma_f32_16x16x32_bf16(al2[mt][ks], bl, acc2[mt][nt], 0, 0, 0);
      }
    }
  }
  #pragma unroll
  for (int mt = 0; mt < 2; mt++) {
    #pragma unroll
    for (int nt = 0; nt < 4; nt++) {
      int c = (w * 4 + nt) * 16 + c0;
      float bb = be[c];
      #pragma unroll
      for (int j = 0; j < 4; j++) {
        int row = mt * 16 + g * 4 + j;
        hE[(size_t)(e0 + row) * H_ + c] = acc2[mt][nt][j] + bb;
      }
    }
  }
}

// ---------------- per-node projection (encoder): oa/ob = x@Wa/Wb ----------------
__global__ __launch_bounds__(128) void node_proj_kernel(const float* __restrict__ x1,
    const float* __restrict__ Wa1, const float* __restrict__ Wb1,
    float* __restrict__ oa, float* __restrict__ ob) {
  constexpr int NT = 16;
  int n0 = blockIdx.x * NT, t = threadIdx.x;
  __shared__ __attribute__((aligned(16))) float xs1[NT * H_];
  #pragma unroll
  for (int u = 0; u < NT; u++) xs1[u * H_ + t] = x1[(size_t)(n0 + u) * H_ + t];
  __syncthreads();
  float aa[NT], ab[NT];
  #pragma unroll
  for (int u = 0; u < NT; u++) { aa[u] = 0.f; ab[u] = 0.f; }
  for (int j4 = 0; j4 < H_ / 4; j4++) {
    int j = j4 * 4;
    float wa0 = Wa1[(j + 0) * H_ + t], wa1 = Wa1[(j + 1) * H_ + t];
    float wa2 = Wa1[(j + 2) * H_ + t], wa3 = Wa1[(j + 3) * H_ + t];
    float wb0 = Wb1[(j + 0) * H_ + t], wb1 = Wb1[(j + 1) * H_ + t];
    float wb2 = Wb1[(j + 2) * H_ + t], wb3 = Wb1[(j + 3) * H_ + t];
    #pragma unroll
    for (int u = 0; u < NT; u++) {
      float4 xv = ((const float4*)(xs1 + u * H_))[j4];
      aa[u] = fmaf(xv.x, wa0, fmaf(xv.y, wa1, fmaf(xv.z, wa2, fmaf(xv.w, wa3, aa[u]))));
      ab[u] = fmaf(xv.x, wb0, fmaf(xv.y, wb1, fmaf(xv.z, wb2, fmaf(xv.w, wb3, ab[u]))));
    }
  }
  #pragma unroll
  for (int u = 0; u < NT; u++) {
    oa[(size_t)(n0 + u) * H_ + t] = aa[u];
    ob[(size_t)(n0 + u) * H_ + t] = ab[u];
  }
}

// ---------------- decoder fused projection ----------------
__global__ __launch_bounds__(128) void node_proj3_kernel(const int* __restrict__ S,
    const float* __restrict__ Ws, const float* __restrict__ din, const float* __restrict__ henc,
    const float* __restrict__ WK2, const float* __restrict__ WV2,
    const float* __restrict__ WK3, const float* __restrict__ WV3,
    float* __restrict__ nKb, float* __restrict__ nVb,
    float* __restrict__ nKe, float* __restrict__ nVe) {
  constexpr int NT = 8;
  int n0 = blockIdx.x * NT, t = threadIdx.x;
  __shared__ __attribute__((aligned(16))) float xs1[NT * H_];  // hS
  __shared__ __attribute__((aligned(16))) float xs2[NT * H_];  // din
  __shared__ __attribute__((aligned(16))) float xs3[NT * H_];  // henc
  #pragma unroll
  for (int u = 0; u < NT; u++) {
    int node = n0 + u;
    xs1[u * H_ + t] = Ws[(size_t)S[node] * H_ + t];
    xs2[u * H_ + t] = din[(size_t)node * H_ + t];
    xs3[u * H_ + t] = henc[(size_t)node * H_ + t];
  }
  __syncthreads();
  float aKb[NT], aVb[NT], aKe[NT], aVe[NT];
  #pragma unroll
  for (int u = 0; u < NT; u++) { aKb[u] = 0.f; aVb[u] = 0.f; aKe[u] = 0.f; aVe[u] = 0.f; }
  for (int j4 = 0; j4 < H_ / 4; j4++) {
    int j = j4 * 4;
    float k20 = WK2[(j + 0) * H_ + t], k21 = WK2[(j + 1) * H_ + t];
    float k22 = WK2[(j + 2) * H_ + t], k23 = WK2[(j + 3) * H_ + t];
    float v20 = WV2[(j + 0) * H_ + t], v21 = WV2[(j + 1) * H_ + t];
    float v22 = WV2[(j + 2) * H_ + t], v23 = WV2[(j + 3) * H_ + t];
    float k30 = WK3[(j + 0) * H_ + t], k31 = WK3[(j + 1) * H_ + t];
    float k32 = WK3[(j + 2) * H_ + t], k33 = WK3[(j + 3) * H_ + t];
    float v30 = WV3[(j + 0) * H_ + t], v31 = WV3[(j + 1) * H_ + t];
    float v32 = WV3[(j + 2) * H_ + t], v33 = WV3[(j + 3) * H_ + t];
    #pragma unroll
    for (int u = 0; u < NT; u++) {
      float4 a = ((const float4*)(xs1 + u * H_))[j4];
      float4 b = ((const float4*)(xs2 + u * H_))[j4];
      float4 c = ((const float4*)(xs3 + u * H_))[j4];
      aKb[u] = fmaf(a.x, k20, fmaf(a.y, k21, fmaf(a.z, k22, fmaf(a.w, k23, aKb[u]))));
      aKb[u] = fmaf(b.x, k30, fmaf(b.y, k31, fmaf(b.z, k32, fmaf(b.w, k33, aKb[u]))));
      aVb[u] = fmaf(a.x, v20, fmaf(a.y, v21, fmaf(a.z, v22, fmaf(a.w, v23, aVb[u]))));
      aVb[u] = fmaf(b.x, v30, fmaf(b.y, v31, fmaf(b.z, v32, fmaf(b.w, v33, aVb[u]))));
      aKe[u] = fmaf(c.x, k30, fmaf(c.y, k31, fmaf(c.z, k32, fmaf(c.w, k33, aKe[u]))));
      aVe[u] = fmaf(c.x, v30, fmaf(c.y, v31, fmaf(c.z, v32, fmaf(c.w, v33, aVe[u]))));
    }
  }
  #pragma unroll
  for (int u = 0; u < NT; u++) {
    size_t g = (size_t)(n0 + u) * H_ + t;
    nKb[g] = aKb[u]; nVb[g] = aVb[u]; nKe[g] = aKe[u]; nVe[g] = aVe[u];
  }
}

// ---------------- weight-fragment prep for FFN W1 (128x512) / W2 (512x128) ----------------
__global__ __launch_bounds__(256) void prep_wfrag2_kernel(const float* __restrict__ eW1,
    const float* __restrict__ eW2, const float* __restrict__ dW1, const float* __restrict__ dW2,
    ushort_t* __restrict__ hiOut, ushort_t* __restrict__ loOut) {
  int m = blockIdx.x;  // 0..11: eW1 l0-2, eW2 l0-2, dW1 l0-2, dW2 l0-2
  const float* W; int C;
  if (m < 3)      { W = eW1 + (size_t)m * FRAG2_;       C = 4 * H_; }
  else if (m < 6) { W = eW2 + (size_t)(m - 3) * FRAG2_; C = H_; }
  else if (m < 9) { W = dW1 + (size_t)(m - 6) * FRAG2_; C = 4 * H_; }
  else            { W = dW2 + (size_t)(m - 9) * FRAG2_; C = H_; }
  ushort_t* hi = hiOut + (size_t)m * FRAG2_;
  ushort_t* lo = loOut + (size_t)m * FRAG2_;
  int ntn = C >> 4;
  int cshift = (C == 512) ? 9 : 7;
  for (int i = 0; i < FRAG2_ / 256; i++) {
    int lin = i * 256 + threadIdx.x;
    int k = lin >> cshift, c = lin & (C - 1);
    float x = W[lin];
    int ks = k >> 5, gk = (k >> 3) & 3, j = k & 7;
    int nt = c >> 4, cc = c & 15;
    int lane = gk * 16 + cc;
    int oidx = ((ks * ntn + nt) * 64 + lane) * 8 + j;
    ushort_t hb = bf16rn(x);
    hi[oidx] = hb;
    lo[oidx] = bf16rn(x - bf16tof(hb));
  }
}

// ---------------- fused graph attention + residual LN — 8 nodes/block, per-node pipeline ----------------
// R12 configuration (measured best: attn ~130us, total 1439us). 8-node weight amortization
// (R11) + per-node {scores -> softmax -> agg} pipeline (R12). hE read 2x from global —
// R13 (LDS stage phase) and R14 (stage-in-scores tee, ANT_=4) both measured slower: traffic
// savings trade ~1:1 against occupancy/amortization/barriers in this structure.
constexpr int ANT_ = 8;
template<bool ENC>
__global__ __launch_bounds__(128) void attn_kernel(const float* __restrict__ hV_in,
    const float* __restrict__ hE, const int* __restrict__ E_idx, const float* __restrict__ mask,
    const float* __restrict__ WQ, const float* __restrict__ WK1T, const float* __restrict__ WV1,
    const float* __restrict__ WO,
    const float* __restrict__ nKb, const float* __restrict__ nVb,
    const float* __restrict__ nKe, const float* __restrict__ nVe,
    float* __restrict__ hV_out) {
  const int node0 = blockIdx.x * ANT_;
  const int b = node0 / N_;
  const int nbase = node0 % N_;          // all 8 nodes share batch b (N_ % ANT_ == 0)
  const int t = threadIdx.x;
  const int g = t >> 5, lane32 = t & 31;
  const int head = g;

  __shared__ __attribute__((aligned(16))) float x0s[ANT_][H_];
  __shared__ __attribute__((aligned(16))) float qs[ANT_][H_];        // q, later ob
  __shared__ __attribute__((aligned(16))) float qkagg[ANT_][4 * H_]; // qk, later agg
  __shared__ float scb[ANT_][NH_ * 32];                              // scores/att, later r
  __shared__ int nbs[ANT_][K_];
  __shared__ float mis[ANT_];
  __shared__ float mst[ANT_], ist[ANT_];

  // stage x0, neighbor lists, masks; pad score slots
  #pragma unroll
  for (int u = 0; u < ANT_; u++) {
    x0s[u][t] = hV_in[(size_t)(node0 + u) * H_ + t];
    if ((t & 31) >= K_) scb[u][t] = NEG_INF_;
  }
  for (int i = t; i < ANT_ * K_; i += 128) nbs[i / K_][i % K_] = E_idx[(size_t)node0 * K_ + i];
  if (t < ANT_) mis[t] = mask[(size_t)b * N_ + nbase + t];
  __syncthreads();

  // q = x0 @ WQ  (weights read once per block; per-node fmaf order = R7)
  {
    float qv[ANT_];
    #pragma unroll
    for (int u = 0; u < ANT_; u++) qv[u] = 0.f;
    for (int j4 = 0; j4 < H_ / 4; j4++) {
      int j = j4 * 4;
      float w0 = WQ[(j + 0) * H_ + t], w1 = WQ[(j + 1) * H_ + t];
      float w2 = WQ[(j + 2) * H_ + t], w3 = WQ[(j + 3) * H_ + t];
      #pragma unroll
      for (int u = 0; u < ANT_; u++) {
        float4 xv = ((const float4*)x0s[u])[j4];
        qv[u] = fmaf(xv.x, w0, fmaf(xv.y, w1, fmaf(xv.z, w2, fmaf(xv.w, w3, qv[u]))));
      }
    }
    #pragma unroll
    for (int u = 0; u < ANT_; u++) qs[u][t] = qv[u];
  }
  __syncthreads();

  // qk[h][t] = sum_{c in head h} WK1T[c*H+t] * q[c]  (per-node order = R7)
  {
    float ak[ANT_][4];
    #pragma unroll
    for (int u = 0; u < ANT_; u++)
      #pragma unroll
      for (int h = 0; h < 4; h++) ak[u][h] = 0.f;
    for (int c = 0; c < 32; c++) {
      float wA = WK1T[(c      ) * H_ + t];
      float wB = WK1T[(c + 32 ) * H_ + t];
      float wC = WK1T[(c + 64 ) * H_ + t];
      float wD = WK1T[(c + 96 ) * H_ + t];
      #pragma unroll
      for (int u = 0; u < ANT_; u++) {
        ak[u][0] = fmaf(wA, qs[u][c      ], ak[u][0]);
        ak[u][1] = fmaf(wB, qs[u][c + 32 ], ak[u][1]);
        ak[u][2] = fmaf(wC, qs[u][c + 64 ], ak[u][2]);
        ak[u][3] = fmaf(wD, qs[u][c + 96 ], ak[u][3]);
      }
    }
    #pragma unroll
    for (int u = 0; u < ANT_; u++)
      #pragma unroll
      for (int h = 0; h < 4; h++) qkagg[u][h * H_ + t] = ak[u][h];
  }
  __syncthreads();

  // per-node pipeline: scores_u -> softmax_u -> agg_u + onode_u (hE tile L2-hot on re-read)
  float onode[ANT_];
  const float scale = 0.17677669529663687f;  // 1/sqrt(32)
  #pragma unroll 1
  for (int u = 0; u < ANT_; u++) {
    const float* heu = hE + (size_t)(node0 + u) * (K_ * H_);
    const float mi = mis[u];
    const int nmod = nbase + u;
    // ---- scores_u: group g handles edges k = g, g+4, ...; per-edge math/butterfly = R7
    {
      float qkv[4][4];
      #pragma unroll
      for (int h = 0; h < 4; h++)
        #pragma unroll
        for (int j = 0; j < 4; j++)
          qkv[h][j] = qkagg[u][h * H_ + lane32 + 32 * j];
      float qv[4];
      #pragma unroll
      for (int h = 0; h < 4; h++) qv[h] = qs[u][lane32 + 32 * h];
      #pragma unroll 1
      for (int kk = 0; kk < 8; kk++) {
        int k = g + 4 * kk;
        if (k >= K_) break;
        int nb = nbs[u][k];
        size_t nbg = (size_t)(b * N_ + nb) * H_ + lane32;
        float gbv[4], gev[4], m2;
        gbv[0] = nKb[nbg]; gbv[1] = nKb[nbg + 32]; gbv[2] = nKb[nbg + 64]; gbv[3] = nKb[nbg + 96];
        if (!ENC) {
          gev[0] = nKe[nbg]; gev[1] = nKe[nbg + 32]; gev[2] = nKe[nbg + 64]; gev[3] = nKe[nbg + 96];
        } else {
          m2 = mi * mask[b * N_ + nb];
        }
        const float* he = heu + k * H_;
        float he0 = he[lane32], he1 = he[lane32 + 32], he2 = he[lane32 + 64], he3 = he[lane32 + 96];
        float pr[4];
        #pragma unroll
        for (int h = 0; h < 4; h++) {
          float ep = fmaf(qkv[h][0], he0,
                     fmaf(qkv[h][1], he1,
                     fmaf(qkv[h][2], he2, qkv[h][3] * he3)));
          if (ENC) {
            pr[h] = fmaf(qv[h], gbv[h], ep);
          } else {
            float ar = (nb < nmod) ? 1.f : 0.f;
            float bw = mi * ar, fw = mi * (1.f - ar);
            float nodek = fmaf(bw, gbv[h], fw * gev[h]);
            pr[h] = fmaf(mi, ep, qv[h] * nodek);
          }
        }
        #pragma unroll
        for (int off = 16; off > 0; off >>= 1)
          #pragma unroll
          for (int h = 0; h < 4; h++)
            pr[h] += __shfl_xor(pr[h], off, 32);
        if (lane32 == 0) {
          #pragma unroll
          for (int h = 0; h < 4; h++) {
            if (ENC) scb[u][h * 32 + k] = (m2 > 0.f) ? pr[h] * scale : NEG_INF_;
            else     scb[u][h * 32 + k] = pr[h] * scale;
          }
        }
      }
    }
    __syncthreads();
    // ---- softmax_u (= R7 per node)
    {
      float s = scb[u][t];
      float mx = s;
      #pragma unroll
      for (int off = 16; off > 0; off >>= 1) mx = fmaxf(mx, __shfl_xor(mx, off, 32));
      float ev = expf(s - mx);
      float sum = ev;
      #pragma unroll
      for (int off = 16; off > 0; off >>= 1) sum += __shfl_xor(sum, off, 32);
      scb[u][t] = ev / sum;
    }
    __syncthreads();
    // ---- agg_u: re-reads heu while L2-hot; k order = R7
    {
      float a0 = 0.f, a1 = 0.f, a2 = 0.f, a3 = 0.f;
      #pragma unroll
      for (int k = 0; k < K_; k++) {
        float hv = heu[k * H_ + t];
        a0 = fmaf(scb[u][0 * 32 + k], hv, a0);
        a1 = fmaf(scb[u][1 * 32 + k], hv, a1);
        a2 = fmaf(scb[u][2 * 32 + k], hv, a2);
        a3 = fmaf(scb[u][3 * 32 + k], hv, a3);
      }
      qkagg[u][0 * H_ + t] = a0;
      qkagg[u][1 * H_ + t] = a1;
      qkagg[u][2 * H_ + t] = a2;
      qkagg[u][3 * H_ + t] = a3;
    }
    // ---- onode_u with KT=10 batching (= R7)
    {
      float on = 0.f;
      for (int kt = 0; kt < K_; kt += 10) {
        float gv[10], gve[10];
        #pragma unroll
        for (int i = 0; i < 10; i++) {
          int nb = nbs[u][kt + i];
          size_t nbg = (size_t)(b * N_ + nb) * H_ + t;
          gv[i] = nVb[nbg];
          if (!ENC) gve[i] = nVe[nbg];
        }
        #pragma unroll
        for (int i = 0; i < 10; i++) {
          int k = kt + i;
          float att = scb[u][head * 32 + k];
          if (ENC) {
            on = fmaf(att, gv[i], on);
          } else {
            int nb = nbs[u][k];
            float ar = (nb < nmod) ? 1.f : 0.f;
            float bw = mi * ar, fw = mi * (1.f - ar);
            on = fmaf(att, fmaf(bw, gv[i], fw * gve[i]), on);
          }
        }
      }
      onode[u] = on;
    }
  }
  __syncthreads();

  // oe[t] = agg_{head} @ WV1[:, t]  (weights once per block; f order = R7)
  float oreg[ANT_];
  {
    float oe[ANT_];
    #pragma unroll
    for (int u = 0; u < ANT_; u++) oe[u] = 0.f;
    for (int f = 0; f < H_; f++) {
      float wv = WV1[f * H_ + t];
      #pragma unroll
      for (int u = 0; u < ANT_; u++)
        oe[u] = fmaf(qkagg[u][head * H_ + f], wv, oe[u]);
    }
    #pragma unroll
    for (int u = 0; u < ANT_; u++)
      oreg[u] = ENC ? (oe[u] + onode[u]) : fmaf(mis[u], oe[u], onode[u]);
  }
  #pragma unroll
  for (int u = 0; u < ANT_; u++) qs[u][t] = oreg[u];   // ob (qs dead after scores)
  __syncthreads();

  // dh = ob @ WO (weights once per block; j4 order = R7); residual
  float rv[ANT_];
  {
    float dh[ANT_];
    #pragma unroll
    for (int u = 0; u < ANT_; u++) dh[u] = 0.f;
    for (int j4 = 0; j4 < H_ / 4; j4++) {
      int j = j4 * 4;
      float w0 = WO[(j + 0) * H_ + t], w1 = WO[(j + 1) * H_ + t];
      float w2 = WO[(j + 2) * H_ + t], w3 = WO[(j + 3) * H_ + t];
      #pragma unroll
      for (int u = 0; u < ANT_; u++) {
        float4 ov = ((const float4*)qs[u])[j4];
        dh[u] = fmaf(ov.x, w0, fmaf(ov.y, w1, fmaf(ov.z, w2, fmaf(ov.w, w3, dh[u]))));
      }
    }
    #pragma unroll
    for (int u = 0; u < ANT_; u++) rv[u] = x0s[u][t] + dh[u];
  }
  #pragma unroll
  for (int u = 0; u < ANT_; u++) scb[u][t] = rv[u];    // r rows (scb dead after onode)
  __syncthreads();

  // row LN stats: 16 threads per node-row (ffn-style)
  {
    int u = t >> 4, li = t & 15;
    float s = 0.f;
    #pragma unroll
    for (int i = 0; i < 8; i++) s += scb[u][li + 16 * i];
    s += __shfl_xor(s, 1, 64); s += __shfl_xor(s, 2, 64);
    s += __shfl_xor(s, 4, 64); s += __shfl_xor(s, 8, 64);
    float mean = s * (1.f / H_);
    float vs = 0.f;
    #pragma unroll
    for (int i = 0; i < 8; i++) {
      float d = scb[u][li + 16 * i] - mean;
      vs = fmaf(d, d, vs);
    }
    vs += __shfl_xor(vs, 1, 64); vs += __shfl_xor(vs, 2, 64);
    vs += __shfl_xor(vs, 4, 64); vs += __shfl_xor(vs, 8, 64);
    if (li == 0) { mst[u] = mean; ist[u] = rsqrtf(vs * (1.f / H_) + 1e-6f); }
  }
  __syncthreads();
  #pragma unroll
  for (int u = 0; u < ANT_; u++)
    hV_out[(size_t)(node0 + u) * H_ + t] = (rv[u] - mst[u]) * ist[u];
}

// ---------------- FFN via split-bf16 MFMA: LN(x + relu(x@W1+b1)@W2+b2) * mask ----------------
constexpr int NTF_ = 8;
__global__ __launch_bounds__(128) void ffn_kernel(float* __restrict__ hV, const float* __restrict__ mask,
    const ushort_t* __restrict__ w1hi, const ushort_t* __restrict__ w1lo,
    const ushort_t* __restrict__ w2hi, const ushort_t* __restrict__ w2lo,
    const float* __restrict__ b1, const float* __restrict__ b2) {
  int n0 = blockIdx.x * NTF_, t = threadIdx.x;
  const int w = t >> 6, l = t & 63, c0 = l & 15, g = l >> 4;
  __shared__ __attribute__((aligned(16))) ushort_t xhi[16 * H_], xlo[16 * H_];
  __shared__ __attribute__((aligned(16))) ushort_t hpl[2][2 * 16 * H_];
  __shared__ float mst[16], ist[16];
  float* obuf = (float*)&hpl[0][0];

  #pragma unroll
  for (int it = 0; it < 2; it++) {
    int id = it * 128 + t;
    int r = id >> 4, u = id & 15;
    short8 h8 = {0,0,0,0,0,0,0,0}, l8 = {0,0,0,0,0,0,0,0};
    if (r < NTF_) {
      const float4* p = (const float4*)(hV + (size_t)(n0 + r) * H_ + u * 8);
      float4 f0 = p[0], f1 = p[1];
      float xv[8] = {f0.x, f0.y, f0.z, f0.w, f1.x, f1.y, f1.z, f1.w};
      #pragma unroll
      for (int e = 0; e < 8; e++) {
        ushort_t hb = bf16rn(xv[e]);
        h8[e] = (short)hb;
        l8[e] = (short)bf16rn(xv[e] - bf16tof(hb));
      }
    }
    int us = u ^ (r & 15);
    *(short8*)&xhi[r * 128 + us * 8] = h8;
    *(short8*)&xlo[r * 128 + us * 8] = l8;
  }
  __syncthreads();

  short8 axh[4], axl[4];
  #pragma unroll
  for (int ks = 0; ks < 4; ks++) {
    int us = ((ks * 4 + g) ^ c0) * 8;
    axh[ks] = *(const short8*)&xhi[c0 * 128 + us];
    axl[ks] = *(const short8*)&xlo[c0 * 128 + us];
  }

  ushort_t* myhhi = &hpl[w][0];
  ushort_t* myhlo = &hpl[w][16 * H_];
  f32x4 accO[8];
  #pragma unroll
  for (int nt = 0; nt < 8; nt++) accO[nt] = f32x4{0.f, 0.f, 0.f, 0.f};

  #pragma unroll
  for (int cc = 0; cc < 2; cc++) {
    int c = 2 * w + cc;
    f32x4 a1[8];
    #pragma unroll
    for (int nt = 0; nt < 8; nt++) a1[nt] = f32x4{0.f, 0.f, 0.f, 0.f};
    #pragma unroll
    for (int ks = 0; ks < 4; ks++) {
      #pragma unroll
      for (int nt = 0; nt < 8; nt++) {
        size_t boff = (size_t)(((ks * 32 + (c * 8 + nt)) * 64 + l) * 8);
        short8 bh = *(const short8*)(w1hi + boff);
        short8 bl = *(const short8*)(w1lo + boff);
        a1[nt] = __builtin_amdgcn_mfma_f32_16x16x32_bf16(axh[ks], bh, a1[nt], 0, 0, 0);
        a1[nt] = __builtin_amdgcn_mfma_f32_16x16x32_bf16(axl[ks], bh, a1[nt], 0, 0, 0);
        a1[nt] = __builtin_amdgcn_mfma_f32_16x16x32_bf16(axh[ks], bl, a1[nt], 0, 0, 0);
        a1[nt] = __builtin_amdgcn_mfma_f32_16x16x32_bf16(axl[ks], bl, a1[nt], 0, 0, 0);
      }
    }
    #pragma unroll
    for (int nt = 0; nt < 8; nt++) {
      int col = nt * 16 + c0;
      float bb = b1[c * 128 + col];
      #pragma unroll
      for (int j = 0; j < 4; j++) {
        int row = g * 4 + j;
        float hv = fmaxf(a1[nt][j] + bb, 0.f);
        ushort_t hb = bf16rn(hv);
        ushort_t lb = bf16rn(hv - bf16tof(hb));
        int us2 = ((col >> 3) ^ row) * 8 + (col & 7);
        myhhi[row * 128 + us2] = hb;
        myhlo[row * 128 + us2] = lb;
      }
    }
    #pragma unroll
    for (int ks = 0; ks < 4; ks++) {
      int us2 = ((ks * 4 + g) ^ c0) * 8;
      short8 ahh = *(const short8*)&myhhi[c0 * 128 + us2];
      short8 ahl = *(const short8*)&myhlo[c0 * 128 + us2];
      #pragma unroll
      for (int nt = 0; nt < 8; nt++) {
        size_t boff = (size_t)((((c * 4 + ks) * 8 + nt) * 64 + l) * 8);
        short8 bh = *(const short8*)(w2hi + boff);
        short8 bl = *(const short8*)(w2lo + boff);
        accO[nt] = __builtin_amdgcn_mfma_f32_16x16x32_bf16(ahh, bh, accO[nt], 0, 0, 0);
        accO[nt] = __builtin_amdgcn_mfma_f32_16x16x32_bf16(ahl, bh, accO[nt], 0, 0, 0);
        accO[nt] = __builtin_amdgcn_mfma_f32_16x16x32_bf16(ahh, bl, accO[nt], 0, 0, 0);
        accO[nt] = __builtin_amdgcn_mfma_f32_16x16x32_bf16(ahl, bl, accO[nt], 0, 0, 0);
      }
    }
  }

  if (w == 0) {
    #pragma unroll
    for (int nt = 0; nt < 8; nt++) {
      #pragma unroll
      for (int j = 0; j < 4; j++) {
        int row = g * 4 + j;
        if (row < NTF_) obuf[row * H_ + nt * 16 + c0] = accO[nt][j];
      }
    }
  }
  __syncthreads();
  if (w == 1) {
    #pragma unroll
    for (int nt = 0; nt < 8; nt++) {
      #pragma unroll
      for (int j = 0; j < 4; j++) {
        int row = g * 4 + j;
        if (row < NTF_) obuf[row * H_ + nt * 16 + c0] += accO[nt][j];
      }
    }
  }
  __syncthreads();

  float rv[NTF_];
  {
    int un = t >> 3, e = t & 7;
    float bb = b2[t];
    #pragma unroll
    for (int u = 0; u < NTF_; u++) {
      int us = (un ^ u) * 8 + e;
      float xr = bf16tof(xhi[u * 128 + us]) + bf16tof(xlo[u * 128 + us]);
      rv[u] = xr + obuf[u * H_ + t] + bb;
    }
  }
  #pragma unroll
  for (int u = 0; u < NTF_; u++) obuf[u * H_ + t] = rv[u];
  __syncthreads();
  {
    int row = t >> 3, li = t & 7;
    float s = 0.f;
    if (row < NTF_) {
      for (int i = 0; i < 16; i++) s += obuf[row * H_ + li + 8 * i];
    }
    s += __shfl_xor(s, 1, 64); s += __shfl_xor(s, 2, 64); s += __shfl_xor(s, 4, 64);
    float mean = s * (1.f / H_);
    float vs = 0.f;
    if (row < NTF_) {
      for (int i = 0; i < 16; i++) {
        float d = obuf[row * H_ + li + 8 * i] - mean;
        vs = fmaf(d, d, vs);
      }
    }
    vs += __shfl_xor(vs, 1, 64); vs += __shfl_xor(vs, 2, 64); vs += __shfl_xor(vs, 4, 64);
    if (li == 0 && row < NTF_) { mst[row] = mean; ist[row] = rsqrtf(vs * (1.f / H_) + 1e-6f); }
  }
  __syncthreads();
  #pragma unroll
  for (int u = 0; u < NTF_; u++) {
    float y = (rv[u] - mst[u]) * ist[u] * mask[n0 + u];
    hV[(size_t)(n0 + u) * H_ + t] = y;
  }
}

// ---------------- output: log_softmax(hV @ W_out + b_out), fp32, 2 nodes/block ----------------
__global__ __launch_bounds__(128) void out_kernel(const float* __restrict__ hV,
    const float* __restrict__ Wout, const float* __restrict__ bout, float* __restrict__ out) {
  int g = threadIdx.x >> 6, t = threadIdx.x & 63;
  int node = blockIdx.x * 2 + g;
  __shared__ float x[2][H_];
  __shared__ float lg[2][V_];
  __shared__ float lse[2];
  x[g][t] = hV[(size_t)node * H_ + t];
  x[g][t + 64] = hV[(size_t)node * H_ + t + 64];
  __syncthreads();
  if (t < V_) {
    float a = bout[t];
    for (int h = 0; h < H_; h++) a = fmaf(x[g][h], Wout[h * V_ + t], a);
    lg[g][t] = a;
  }
  __syncthreads();
  if (t == 0) {
    float mx = -3.4e38f;
    for (int v = 0; v < V_; v++) mx = fmaxf(mx, lg[g][v]);
    float s = 0.f;
    for (int v = 0; v < V_; v++) s += expf(lg[g][v] - mx);
    lse[g] = mx + logf(s);
  }
  __syncthreads();
  if (t < V_) out[(size_t)node * V_ + t] = lg[g][t] - lse[g];
}

// ---------------- host ----------------
extern "C" void kernel_launch(void* const* d_in, const int* in_sizes, int n_in,
                              void* d_out, int out_size, void* d_ws, size_t ws_size,
                              hipStream_t stream) {
  const float* X    = (const float*)d_in[0];
  const float* mask = (const float*)d_in[1];
  const int*   S    = (const int*)d_in[2];
  const float* Wfn  = (const float*)d_in[3];
  const float* bfn  = (const float*)d_in[4];
  const float* Wfe  = (const float*)d_in[5];
  const float* bfe  = (const float*)d_in[6];
  const float* Wv   = (const float*)d_in[7];
  const float* bv   = (const float*)d_in[8];
  const float* We   = (const float*)d_in[9];
  const float* be   = (const float*)d_in[10];
  const float* Ws   = (const float*)d_in[11];
  const float* eWQ  = (const float*)d_in[12];
  const float* eWK  = (const float*)d_in[13];
  const float* eWV  = (const float*)d_in[14];
  const float* eWO  = (const float*)d_in[15];
  const float* eW1  = (const float*)d_in[16];
  const float* eb1  = (const float*)d_in[17];
  const float* eW2  = (const float*)d_in[18];
  const float* eb2  = (const float*)d_in[19];
  const float* dWQ  = (const float*)d_in[20];
  const float* dWK  = (const float*)d_in[21];
  const float* dWV  = (const float*)d_in[22];
  const float* dWO  = (const float*)d_in[23];
  const float* dW1  = (const float*)d_in[24];
  const float* db1  = (const float*)d_in[25];
  const float* dW2  = (const float*)d_in[26];
  const float* db2  = (const float*)d_in[27];
  const float* Wout = (const float*)d_in[28];
  const float* bout = (const float*)d_in[29];
  float* out = (float*)d_out;

  char* w = (char*)d_ws;
  int*    eidx = (int*)w;     w += (size_t)BN_ * K_ * 4;
  float*  dnb  = (float*)w;   w += (size_t)BN_ * K_ * 4;
  float*  vf   = (float*)w;   w += (size_t)BN_ * 6 * 4;
  float*  hVa  = (float*)w;   w += (size_t)BN_ * H_ * 4;
  float*  hVb  = (float*)w;   w += (size_t)BN_ * H_ * 4;
  float*  hVc  = (float*)w;   w += (size_t)BN_ * H_ * 4;
  float*  nKb  = (float*)w;   w += (size_t)BN_ * H_ * 4;
  float*  nVb  = (float*)w;   w += (size_t)BN_ * H_ * 4;
  float*  nKe  = (float*)w;   w += (size_t)BN_ * H_ * 4;
  float*  nVe  = (float*)w;   w += (size_t)BN_ * H_ * 4;
  float*  hE   = (float*)w;   w += (size_t)BN_ * K_ * H_ * 4;
  float*  wkt  = (float*)w;   w += (size_t)6 * FRAG_ * 4;       // WK1^T, 6 layers
  ushort_t* wf2Hi = (ushort_t*)w; w += (size_t)12 * FRAG2_ * 2;
  ushort_t* wf2Lo = (ushort_t*)w; w += (size_t)12 * FRAG2_ * 2;
  ushort_t* feHi = (ushort_t*)w; w += (size_t)4096 * 2;
  ushort_t* feLo = (ushort_t*)w; w += (size_t)4096 * 2;
  ushort_t* weHi = (ushort_t*)w; w += (size_t)FRAG_ * 2;
  ushort_t* weLo = (ushort_t*)w; w += (size_t)FRAG_ * 2;

  topk_kernel<<<BN_ / TQ_, 256, 0, stream>>>(X, mask, eidx, dnb);
  dihedral_kernel<<<(BN_ + 255) / 256, 256, 0, stream>>>(X, vf);
  node_embed_kernel<<<BN_, H_, 0, stream>>>(vf, Wfn, bfn, Wv, bv, hVa);
  prep_edge_w_kernel<<<2, 256, 0, stream>>>(Wfe, We, feHi, feLo, weHi, weLo);
  edge_embed_kernel<<<BN_ * K_ / EEB_, 128, 0, stream>>>(eidx, dnb, feHi, feLo, bfe, weHi, weLo, be, hE);
  prep_wkt_kernel<<<6, 256, 0, stream>>>(eWK, dWK, wkt);
  prep_wfrag2_kernel<<<12, 256, 0, stream>>>(eW1, eW2, dW1, dW2, wf2Hi, wf2Lo);

  // encoder: a->b, b->a, a->b
  float* cur = hVa; float* nxt = hVb;
  for (int l = 0; l < 3; l++) {
    const float* WK = eWK + (size_t)l * 2 * H_ * H_;
    const float* WV = eWV + (size_t)l * 2 * H_ * H_;
    node_proj_kernel<<<BN_ / 16, H_, 0, stream>>>(cur,
        WK + (size_t)H_ * H_, WV + (size_t)H_ * H_, nKb, nVb);
    attn_kernel<true><<<BN_ / ANT_, 128, 0, stream>>>(cur, hE, eidx, mask,
        eWQ + (size_t)l * H_ * H_,
        wkt + (size_t)l * FRAG_,
        WV,                               // WV1: first HxH block, original layout
        eWO + (size_t)l * H_ * H_,
        nKb, nVb, nullptr, nullptr, nxt);
    ffn_kernel<<<BN_ / NTF_, 128, 0, stream>>>(nxt, mask,
        wf2Hi + (size_t)l * FRAG2_, wf2Lo + (size_t)l * FRAG2_,
        wf2Hi + (size_t)(3 + l) * FRAG2_, wf2Lo + (size_t)(3 + l) * FRAG2_,
        eb1 + (size_t)l * 4 * H_, eb2 + (size_t)l * H_);
    float* tmp = cur; cur = nxt; nxt = tmp;
  }
  float* henc = cur;  // = hVb
  // decoder: henc->a, a->c, c->a (henc preserved)
  float* din = henc;
  float* douts[3] = { hVa, hVc, hVa };
  for (int l = 0; l < 3; l++) {
    const float* WK = dWK + (size_t)l * 3 * H_ * H_;
    const float* WV = dWV + (size_t)l * 3 * H_ * H_;
    node_proj3_kernel<<<BN_ / 8, H_, 0, stream>>>(S, Ws, din, henc,
        WK + (size_t)H_ * H_, WV + (size_t)H_ * H_,
        WK + (size_t)2 * H_ * H_, WV + (size_t)2 * H_ * H_,
        nKb, nVb, nKe, nVe);
    attn_kernel<false><<<BN_ / ANT_, 128, 0, stream>>>(din, hE, eidx, mask,
        dWQ + (size_t)l * H_ * H_,
        wkt + (size_t)(3 + l) * FRAG_,
        WV,                               // WV1: first HxH block, original layout
        dWO + (size_t)l * H_ * H_,
        nKb, nVb, nKe, nVe, douts[l]);
    ffn_kernel<<<BN_ / NTF_, 128, 0, stream>>>(douts[l], mask,
        wf2Hi + (size_t)(6 + l) * FRAG2_, wf2Lo + (size_t)(6 + l) * FRAG2_,
        wf2Hi + (size_t)(9 + l) * FRAG2_, wf2Lo + (size_t)(9 + l) * FRAG2_,
        db1 + (size_t)l * 4 * H_, db2 + (size_t)l * H_);
    din = douts[l];
  }
  out_kernel<<<BN_ / 2, 128, 0, stream>>>(din, Wout, bout, out);
}